// Round 1
// baseline (1814.698 us; speedup 1.0000x reference)
//
#include <hip/hip_runtime.h>
#include <math.h>

// Problem constants (match reference)
#define N_ENT     20000
#define N_RELN    400
#define N_TIME    366
#define N_META    800
#define NE        200000
#define NPE       80000
// feature dims: ENT=160, REL=160, TIME=80; DIN_E=400, DIN_R=320

// ---------------------------------------------------------------------------
// Big GEMM: C[M,160] = A[M,160] @ B[160,160] (+ bias), batched over blockIdx.z
// BM=64 rows/block, BK=40, 256 threads, each thread 8 rows x 5 cols.
// LDS: Bs 40x160 (25.6KB) + As 64x40 (10.2KB) = 35.8KB -> 4 blocks/CU.
// B-tile reads: lanes tx=0..31 stride-1 -> conflict-free; A-tile reads 2-way
// broadcast (free per m136).
// ---------------------------------------------------------------------------
struct BigBatch {
    const float* B[3];
    const float* bias[3];
    float*       C[3];
};

__global__ __launch_bounds__(256) void gemm_big(const float* __restrict__ A, int M, BigBatch bb)
{
    __shared__ float Bs[40][160];
    __shared__ float As[64][40];
    const int j = blockIdx.z;
    const float* __restrict__ Bm   = bb.B[j];
    const float* __restrict__ bias = bb.bias[j];
    float* __restrict__ C          = bb.C[j];
    const int m0 = blockIdx.x * 64;
    const int t  = threadIdx.x;
    const int tx = t & 31, ty = t >> 5;

    float acc[8][5];
#pragma unroll
    for (int r = 0; r < 8; ++r)
#pragma unroll
        for (int c = 0; c < 5; ++c) acc[r][c] = 0.f;

    for (int k0 = 0; k0 < 160; k0 += 40) {
        // load B tile: 40x160 = 6400 floats = 25 per thread
#pragma unroll
        for (int i = 0; i < 25; ++i) {
            int idx = t + i * 256;
            int kk = idx / 160, nn = idx - kk * 160;
            Bs[kk][nn] = Bm[(k0 + kk) * 160 + nn];
        }
        // load A tile: 64x40 = 2560 floats = 10 per thread
#pragma unroll
        for (int i = 0; i < 10; ++i) {
            int idx = t + i * 256;
            int mm = idx / 40, kk = idx - mm * 40;
            int row = m0 + mm;
            As[mm][kk] = (row < M) ? A[(size_t)row * 160 + k0 + kk] : 0.f;
        }
        __syncthreads();
#pragma unroll 4
        for (int kk = 0; kk < 40; ++kk) {
            float b0 = Bs[kk][tx], b1 = Bs[kk][tx + 32], b2 = Bs[kk][tx + 64],
                  b3 = Bs[kk][tx + 96], b4 = Bs[kk][tx + 128];
#pragma unroll
            for (int r = 0; r < 8; ++r) {
                float a = As[ty * 8 + r][kk];
                acc[r][0] = fmaf(a, b0, acc[r][0]);
                acc[r][1] = fmaf(a, b1, acc[r][1]);
                acc[r][2] = fmaf(a, b2, acc[r][2]);
                acc[r][3] = fmaf(a, b3, acc[r][3]);
                acc[r][4] = fmaf(a, b4, acc[r][4]);
            }
        }
        __syncthreads();
    }
    float bv[5] = {0.f, 0.f, 0.f, 0.f, 0.f};
    if (bias) {
        bv[0] = bias[tx]; bv[1] = bias[tx + 32]; bv[2] = bias[tx + 64];
        bv[3] = bias[tx + 96]; bv[4] = bias[tx + 128];
    }
#pragma unroll
    for (int r = 0; r < 8; ++r) {
        int row = m0 + ty * 8 + r;
        if (row < M) {
            float* Cr = C + (size_t)row * 160;
            Cr[tx]       = acc[r][0] + bv[0];
            Cr[tx + 32]  = acc[r][1] + bv[1];
            Cr[tx + 64]  = acc[r][2] + bv[2];
            Cr[tx + 96]  = acc[r][3] + bv[3];
            Cr[tx + 128] = acc[r][4] + bv[4];
        }
    }
}

// ---------------------------------------------------------------------------
// Small GEMM batch: thread-per-(row, 4-col group); everything L1/L2 resident.
// ---------------------------------------------------------------------------
struct SmallDesc {
    const float* A;
    const float* B;
    const float* bias;
    float*       C;
    int M, K, N, ldb, relu;
};
struct SmallBatch { SmallDesc d[6]; };

__global__ __launch_bounds__(256) void gemm_small_batch(SmallBatch sb)
{
    SmallDesc dd = sb.d[blockIdx.y];
    int tid = blockIdx.x * 256 + threadIdx.x;
    int ng = dd.N >> 2;
    int m = tid / ng;
    if (m >= dd.M) return;
    int g = tid - m * ng;
    const float* __restrict__ Ar = dd.A + (size_t)m * dd.K;
    const float* __restrict__ Bp = dd.B + g * 4;
    float4 acc;
    if (dd.bias) acc = *(const float4*)(dd.bias + g * 4);
    else { acc.x = 0.f; acc.y = 0.f; acc.z = 0.f; acc.w = 0.f; }
    for (int k = 0; k < dd.K; ++k) {
        float a = Ar[k];
        float4 b = *(const float4*)(Bp + (size_t)k * dd.ldb);
        acc.x = fmaf(a, b.x, acc.x);
        acc.y = fmaf(a, b.y, acc.y);
        acc.z = fmaf(a, b.z, acc.z);
        acc.w = fmaf(a, b.w, acc.w);
    }
    if (dd.relu) {
        acc.x = fmaxf(acc.x, 0.f); acc.y = fmaxf(acc.y, 0.f);
        acc.z = fmaxf(acc.z, 0.f); acc.w = fmaxf(acc.w, 0.f);
    }
    *(float4*)(dd.C + (size_t)m * dd.N + g * 4) = acc;
}

// ---------------------------------------------------------------------------
// CSR build: count -> exclusive scan (single block) -> scatter permutation
// ---------------------------------------------------------------------------
__global__ void count_deg(const int* __restrict__ d, int E, int* __restrict__ cnt)
{
    int e = blockIdx.x * 256 + threadIdx.x;
    if (e < E) atomicAdd(&cnt[d[e]], 1);
}

__global__ __launch_bounds__(256) void scan_excl(const int* __restrict__ cnt, int* __restrict__ rowptr, int n)
{
    __shared__ int ssum[256];
    int t = threadIdx.x;
    int chunk = (n + 255) / 256;
    int s0 = t * chunk; if (s0 > n) s0 = n;
    int s1 = s0 + chunk; if (s1 > n) s1 = n;
    int local = 0;
    for (int i = s0; i < s1; ++i) local += cnt[i];
    ssum[t] = local;
    __syncthreads();
    if (t == 0) {
        int acc = 0;
        for (int i = 0; i < 256; ++i) { int v = ssum[i]; ssum[i] = acc; acc += v; }
        rowptr[n] = acc;
    }
    __syncthreads();
    int acc = ssum[t];
    for (int i = s0; i < s1; ++i) { rowptr[i] = acc; acc += cnt[i]; }
}

__global__ void scatter_perm(const int* __restrict__ d, int E, int* __restrict__ cursor, int* __restrict__ perm)
{
    int e = blockIdx.x * 256 + threadIdx.x;
    if (e < E) {
        int p = atomicAdd(&cursor[d[e]], 1);
        perm[p] = e;
    }
}

// ---------------------------------------------------------------------------
// Ent-graph aggregation (CSR, no atomics), fused with mean-divide + ReLU.
// Thread = (node, 4-col group); 40 consecutive threads share a node so the
// 640B gathered rows are read coalesced.
// H (inout) already holds ent@WS + bias (from gemm_big).
// ---------------------------------------------------------------------------
__global__ __launch_bounds__(256) void agg_ent_csr(
    const int* __restrict__ rowptr, const int* __restrict__ perm,
    const int* __restrict__ src, const int* __restrict__ e_rel,
    const int* __restrict__ e_time, const int* __restrict__ e_inv,
    const float* __restrict__ arI, const float* __restrict__ arO,
    const float* __restrict__ aeI, const float* __restrict__ aeO,
    const float* __restrict__ atI, const float* __restrict__ atO,
    float* __restrict__ H, int relu)
{
    int tid = blockIdx.x * 256 + threadIdx.x;
    int n = tid / 40;
    if (n >= N_ENT) return;
    int g = tid - n * 40;
    int c = g * 4;
    int b = rowptr[n], e = rowptr[n + 1];
    float ax = 0.f, ay = 0.f, az = 0.f, aw = 0.f;
    for (int j = b; j < e; ++j) {
        int eid = perm[j];
        int inv = e_inv[eid];
        const float* pr = (inv ? arO : arI) + (size_t)e_rel[eid] * 160 + c;
        const float* pe = (inv ? aeO : aeI) + (size_t)src[eid] * 160 + c;
        const float* pt = (inv ? atO : atI) + (size_t)e_time[eid] * 160 + c;
        float4 vr = *(const float4*)pr;
        float4 ve = *(const float4*)pe;
        float4 vt = *(const float4*)pt;
        ax += vr.x + ve.x + vt.x;
        ay += vr.y + ve.y + vt.y;
        az += vr.z + ve.z + vt.z;
        aw += vr.w + ve.w + vt.w;
    }
    size_t idx = (size_t)n * 160 + c;
    float4 h = *(const float4*)(H + idx);
    if (e > b) {
        float s = 1.0f / (float)(e - b);
        h.x = fmaf(ax, s, h.x); h.y = fmaf(ay, s, h.y);
        h.z = fmaf(az, s, h.z); h.w = fmaf(aw, s, h.w);
    }
    if (relu) {
        h.x = fmaxf(h.x, 0.f); h.y = fmaxf(h.y, 0.f);
        h.z = fmaxf(h.z, 0.f); h.w = fmaxf(h.w, 0.f);
    }
    *(float4*)(H + idx) = h;
}

// ---------------------------------------------------------------------------
// Rel-graph aggregation: avg degree 200 -> 16-way segmented per node, partial
// sums atomically added into zeroed agg (only 1M atomics/layer).
// ---------------------------------------------------------------------------
__global__ __launch_bounds__(256) void agg_rel_seg(
    const int* __restrict__ rowptr, const int* __restrict__ perm,
    const int* __restrict__ p_src, const int* __restrict__ p_rel, const int* __restrict__ p_inv,
    const float* __restrict__ bmI, const float* __restrict__ bmO,
    const float* __restrict__ brI, const float* __restrict__ brO,
    float* __restrict__ agg)
{
    int tid = blockIdx.x * 256 + threadIdx.x;
    int g = tid % 40;
    int rest = tid / 40;
    int s = rest & 15;
    int n = rest >> 4;
    if (n >= N_RELN) return;
    int c = g * 4;
    int b = rowptr[n], e = rowptr[n + 1];
    float ax = 0.f, ay = 0.f, az = 0.f, aw = 0.f;
    for (int j = b + s; j < e; j += 16) {
        int eid = perm[j];
        int inv = p_inv[eid];
        const float* pm = (inv ? bmO : bmI) + (size_t)p_rel[eid] * 160 + c;
        const float* pr = (inv ? brO : brI) + (size_t)p_src[eid] * 160 + c;
        float4 vm = *(const float4*)pm;
        float4 vr = *(const float4*)pr;
        ax += vm.x + vr.x; ay += vm.y + vr.y;
        az += vm.z + vr.z; aw += vm.w + vr.w;
    }
    float* o = agg + (size_t)n * 160 + c;
    atomicAdd(o + 0, ax); atomicAdd(o + 1, ay);
    atomicAdd(o + 2, az); atomicAdd(o + 3, aw);
}

__global__ __launch_bounds__(256) void finalize_rel(
    float* __restrict__ H, const float* __restrict__ agg,
    const int* __restrict__ rowptr, int nNodes, int relu)
{
    int tid = blockIdx.x * 256 + threadIdx.x;
    int n = tid / 40;
    if (n >= nNodes) return;
    int g = tid - n * 40;
    size_t idx = (size_t)n * 160 + g * 4;
    int d = rowptr[n + 1] - rowptr[n];
    float4 h = *(const float4*)(H + idx);
    if (d > 0) {
        float s = 1.0f / (float)d;
        float4 a = *(const float4*)(agg + idx);
        h.x = fmaf(a.x, s, h.x); h.y = fmaf(a.y, s, h.y);
        h.z = fmaf(a.z, s, h.z); h.w = fmaf(a.w, s, h.w);
    }
    if (relu) {
        h.x = fmaxf(h.x, 0.f); h.y = fmaxf(h.y, 0.f);
        h.z = fmaxf(h.z, 0.f); h.w = fmaxf(h.w, 0.f);
    }
    *(float4*)(H + idx) = h;
}

// z = mean + noise * exp(log_std)
__global__ void sample_k(const float* __restrict__ mean, const float* __restrict__ logstd,
                         const float* __restrict__ noise, float* __restrict__ z, int n)
{
    int i = blockIdx.x * 256 + threadIdx.x;
    if (i < n) z[i] = fmaf(noise[i], expf(logstd[i]), mean[i]);
}

// ---------------------------------------------------------------------------
extern "C" void kernel_launch(void* const* d_in, const int* in_sizes, int n_in,
                              void* d_out, int out_size, void* d_ws, size_t ws_size,
                              hipStream_t stream)
{
    const float* ent0   = (const float*)d_in[0];
    const float* rel0   = (const float*)d_in[1];
    const float* tim0   = (const float*)d_in[2];
    const float* meta0  = (const float*)d_in[3];
    const float* noiseE = (const float*)d_in[4];
    const float* noiseR = (const float*)d_in[5];
    const float* entWI  = (const float*)d_in[6];
    const float* entWIb = (const float*)d_in[7];
    const float* entWO  = (const float*)d_in[8];
    const float* entWOb = (const float*)d_in[9];
    const float* entWS  = (const float*)d_in[10];
    const float* entWSb = (const float*)d_in[11];
    const float* entWT  = (const float*)d_in[12];
    const float* entWTb = (const float*)d_in[13];
    const float* relWI  = (const float*)d_in[14];
    const float* relWIb = (const float*)d_in[15];
    const float* relWO  = (const float*)d_in[16];
    const float* relWOb = (const float*)d_in[17];
    const float* relWS  = (const float*)d_in[18];
    const float* relWSb = (const float*)d_in[19];
    const float* relWM  = (const float*)d_in[20];
    const float* relWMb = (const float*)d_in[21];
    const int* src    = (const int*)d_in[22];
    const int* dst    = (const int*)d_in[23];
    const int* e_rel  = (const int*)d_in[24];
    const int* e_time = (const int*)d_in[25];
    const int* e_inv  = (const int*)d_in[26];
    const int* p_src  = (const int*)d_in[27];
    const int* p_dst  = (const int*)d_in[28];
    const int* p_rel  = (const int*)d_in[29];
    const int* p_inv  = (const int*)d_in[30];

    float* out = (float*)d_out;
    float* OUT_ent   = out + 0;
    float* OUT_ento  = out + 3200000;
    float* OUT_rel   = out + 6400000;
    float* OUT_relo  = out + 6464000;
    float* OUT_tim   = out + 6528000;
    float* OUT_timo  = out + 6557280;
    float* OUT_meta  = out + 6586560;
    float* OUT_metao = out + 6714560;

    // ---- workspace carve-out (~57 MB) ----
    char* wsp = (char*)d_ws;
    size_t off = 0;
    auto allocF = [&](size_t n) -> float* {
        float* p = (float*)(wsp + off);
        off += ((n * sizeof(float) + 255) & ~(size_t)255);
        return p;
    };
    auto allocI = [&](size_t n) -> int* {
        int* p = (int*)(wsp + off);
        off += ((n * sizeof(int) + 255) & ~(size_t)255);
        return p;
    };
    float* AI      = allocF(3200000);   // ent-part WI precompute
    float* AO      = allocF(3200000);   // ent-part WO precompute
    float* B1v     = allocF(3200000);   // ent1 / logstd_e / ent_o1
    float* B5v     = allocF(3200000);   // mean_e / z_e
    float* tim1    = allocF(29280);
    float* tim_o1  = allocF(29280);
    float* rel1    = allocF(64000);
    float* rel_o1  = allocF(64000);
    float* meta1   = allocF(128000);
    float* meta_o1 = allocF(128000);
    float* arI     = allocF(64000);     // rel-part precompute (+bias) for ent layer
    float* arO     = allocF(64000);
    float* atI     = allocF(58560);     // time-part precompute for ent layer
    float* atO     = allocF(58560);
    float* bmI     = allocF(128000);    // meta-part precompute (+bias) for rel layer
    float* bmO     = allocF(128000);
    float* brI     = allocF(64000);     // rel-part precompute for rel layer
    float* brO     = allocF(64000);
    float* aggR    = allocF(64000);
    float* meanR   = allocF(64000);
    float* logstdR = allocF(64000);
    float* zR      = allocF(64000);
    int* cntE    = allocI(N_ENT);
    int* rowptrE = allocI(N_ENT + 1);
    int* cursorE = allocI(N_ENT);
    int* permE   = allocI(NE);
    int* cntR    = allocI(N_RELN);
    int* rowptrR = allocI(N_RELN + 1);
    int* cursorR = allocI(N_RELN);
    int* permR   = allocI(NPE);
    if (ws_size < off) return;  // loud failure rather than silent corruption

    // ---- CSR build (per launch; graph is static but no cross-call state) ----
    hipMemsetAsync(cntE, 0, N_ENT * sizeof(int), stream);
    hipMemsetAsync(cntR, 0, N_RELN * sizeof(int), stream);
    count_deg<<<(NE + 255) / 256, 256, 0, stream>>>(dst, NE, cntE);
    count_deg<<<(NPE + 255) / 256, 256, 0, stream>>>(p_dst, NPE, cntR);
    scan_excl<<<1, 256, 0, stream>>>(cntE, rowptrE, N_ENT);
    scan_excl<<<1, 256, 0, stream>>>(cntR, rowptrR, N_RELN);
    hipMemcpyAsync(cursorE, rowptrE, N_ENT * sizeof(int), hipMemcpyDeviceToDevice, stream);
    hipMemcpyAsync(cursorR, rowptrR, N_RELN * sizeof(int), hipMemcpyDeviceToDevice, stream);
    scatter_perm<<<(NE + 255) / 256, 256, 0, stream>>>(dst, NE, cursorE, permE);
    scatter_perm<<<(NPE + 255) / 256, 256, 0, stream>>>(p_dst, NPE, cursorR, permR);

    // ---- layer helpers ----
    // ent weight strides: WI/WO layer base li*400*160; ent-part rows 160..319
    // (+25600), time-part rows 320..399 (+51200); WS li*25600; WT li*6400.
    auto ent_layer = [&](int li, const float* entIn, const float* relIn, const float* timIn,
                         float* entOut, float* timOut, int act) {
        const float* WI = entWI + (size_t)li * 64000;
        const float* WO = entWO + (size_t)li * 64000;
        BigBatch bb;
        bb.B[0] = WI + 25600;                bb.bias[0] = nullptr;            bb.C[0] = AI;
        bb.B[1] = WO + 25600;                bb.bias[1] = nullptr;            bb.C[1] = AO;
        bb.B[2] = entWS + (size_t)li * 25600; bb.bias[2] = entWSb + li * 160; bb.C[2] = entOut;
        gemm_big<<<dim3(313, 1, 3), 256, 0, stream>>>(entIn, N_ENT, bb);
        SmallBatch sb{};
        sb.d[0] = SmallDesc{relIn, WI,          entWIb + li * 160, arI, N_RELN, 160, 160, 160, 0};
        sb.d[1] = SmallDesc{relIn, WO,          entWOb + li * 160, arO, N_RELN, 160, 160, 160, 0};
        sb.d[2] = SmallDesc{timIn, WI + 51200,  nullptr,           atI, N_TIME, 80, 160, 160, 0};
        sb.d[3] = SmallDesc{timIn, WO + 51200,  nullptr,           atO, N_TIME, 80, 160, 160, 0};
        int ns = 4;
        if (timOut) {
            sb.d[4] = SmallDesc{timIn, entWT + (size_t)li * 6400, entWTb + li * 80,
                                timOut, N_TIME, 80, 80, 80, act};
            ns = 5;
        }
        gemm_small_batch<<<dim3(63, ns), 256, 0, stream>>>(sb);
        agg_ent_csr<<<(N_ENT * 40 + 255) / 256, 256, 0, stream>>>(
            rowptrE, permE, src, e_rel, e_time, e_inv, arI, arO, AI, AO, atI, atO, entOut, act);
    };

    // rel weight strides: WI/WO layer base li*320*160; rel-part rows 160..319
    // (+25600); WS/WM li*25600.
    auto rel_layer = [&](int li, const float* relIn, const float* metaIn,
                         float* relOut, float* metaOut, int act) {
        const float* WI = relWI + (size_t)li * 51200;
        const float* WO = relWO + (size_t)li * 51200;
        SmallBatch sb{};
        sb.d[0] = SmallDesc{metaIn, WI,         relWIb + li * 160, bmI, N_META, 160, 160, 160, 0};
        sb.d[1] = SmallDesc{metaIn, WO,         relWOb + li * 160, bmO, N_META, 160, 160, 160, 0};
        sb.d[2] = SmallDesc{relIn,  WI + 25600, nullptr,           brI, N_RELN, 160, 160, 160, 0};
        sb.d[3] = SmallDesc{relIn,  WO + 25600, nullptr,           brO, N_RELN, 160, 160, 160, 0};
        sb.d[4] = SmallDesc{relIn,  relWS + (size_t)li * 25600, relWSb + li * 160,
                            relOut, N_RELN, 160, 160, 160, 0};
        int ns = 5;
        if (metaOut) {
            sb.d[5] = SmallDesc{metaIn, relWM + (size_t)li * 25600, relWMb + li * 160,
                                metaOut, N_META, 160, 160, 160, act};
            ns = 6;
        }
        gemm_small_batch<<<dim3(125, ns), 256, 0, stream>>>(sb);
        hipMemsetAsync(aggR, 0, (size_t)N_RELN * 160 * sizeof(float), stream);
        agg_rel_seg<<<(N_RELN * 16 * 40 + 255) / 256, 256, 0, stream>>>(
            rowptrR, permR, p_src, p_rel, p_inv, bmI, bmO, brI, brO, aggR);
        finalize_rel<<<(N_RELN * 40 + 255) / 256, 256, 0, stream>>>(relOut, aggR, rowptrR, N_RELN, act);
    };

    // ---- encoder ----
    ent_layer(0, ent0, rel0, tim0, B1v, tim1, 1);
    rel_layer(0, rel0, meta0, rel1, meta1, 1);
    ent_layer(1, B1v, rel1, tim1, OUT_ent, OUT_tim, 0);
    rel_layer(1, rel1, meta1, OUT_rel, OUT_meta, 0);
    // ---- variational heads (indices 4=mean, 5=log_std; t/m discarded) ----
    ent_layer(4, OUT_ent, OUT_rel, OUT_tim, B5v, nullptr, 0);   // mean_e
    ent_layer(5, OUT_ent, OUT_rel, OUT_tim, B1v, nullptr, 0);   // log_std_e
    rel_layer(4, OUT_rel, OUT_meta, meanR, nullptr, 0);
    rel_layer(5, OUT_rel, OUT_meta, logstdR, nullptr, 0);
    sample_k<<<(3200000 + 255) / 256, 256, 0, stream>>>(B5v, B1v, noiseE, B5v, 3200000); // z_e
    sample_k<<<(64000 + 255) / 256, 256, 0, stream>>>(meanR, logstdR, noiseR, zR, 64000); // z_r
    // ---- decoder (layers 2,3) ----
    ent_layer(2, B5v, zR, OUT_tim, B1v, tim_o1, 1);
    rel_layer(2, zR, OUT_meta, rel_o1, meta_o1, 1);
    ent_layer(3, B1v, rel_o1, tim_o1, OUT_ento, OUT_timo, 0);
    rel_layer(3, rel_o1, meta_o1, OUT_relo, OUT_metao, 0);
}

// Round 2
// 1517.053 us; speedup vs baseline: 1.1962x; 1.1962x over previous
//
#include <hip/hip_runtime.h>
#include <math.h>

// Problem constants (match reference)
#define N_ENT     20000
#define N_RELN    400
#define N_TIME    366
#define N_META    800
#define NE        200000
#define NPE       80000
// feature dims: ENT=160, REL=160, TIME=80; DIN_E=400, DIN_R=320

// ---------------------------------------------------------------------------
// Big GEMM v2: C[M,160] = A[M,160] @ B[160,160] (+ bias), batched blockIdx.z.
// 128 threads (2 waves), BM=64, BK=32. Per-thread 16 rows x 5 cols (80 acc).
// A staged TRANSPOSED: At[32][66] (stride 66 -> float2 reads 8B-aligned;
// staging writes 2-way bank = free). B tile Bs[32][160], b32 reads tx-indexed
// conflict-free. Per kk: 5 b32 + 8 b64 LDS (~81cyc) vs 80 FMA (160cyc) ->
// FMA-bound. LDS 28.9KB -> 5 blocks/CU cap.
// ---------------------------------------------------------------------------
struct BigBatch {
    const float* B[3];
    const float* bias[3];
    float*       C[3];
};

__global__ __launch_bounds__(128, 3) void gemm_big(const float* __restrict__ A, int M, BigBatch bb)
{
    __shared__ float Bs[32][160];
    __shared__ float At[32][66];
    const int z = blockIdx.z;
    const float* __restrict__ Bm   = bb.B[z];
    const float* __restrict__ bias = bb.bias[z];
    float* __restrict__ C          = bb.C[z];
    const int m0 = blockIdx.x * 64;
    const int t  = threadIdx.x;
    const int tx = t & 31, ty = t >> 5;   // ty in 0..3 -> rows ty*16..+15

    float acc[16][5];
#pragma unroll
    for (int r = 0; r < 16; ++r)
#pragma unroll
        for (int c = 0; c < 5; ++c) acc[r][c] = 0.f;

    for (int k0 = 0; k0 < 160; k0 += 32) {
        // stage B: 32x160 = 1280 float4, 10 per thread (coalesced, cf writes)
#pragma unroll
        for (int i = 0; i < 10; ++i) {
            int idx = t + i * 128;            // 0..1279
            int kk = idx / 40, c4 = idx - kk * 40;
            float4 v = *(const float4*)(Bm + (size_t)(k0 + kk) * 160 + c4 * 4);
            *(float4*)&Bs[kk][c4 * 4] = v;
        }
        // stage A transposed: 64 rows x 32 k = 512 float4, 4 per thread
#pragma unroll
        for (int i = 0; i < 4; ++i) {
            int idx = t + i * 128;            // 0..511
            int row = idx >> 3, kg = idx & 7; // row 0..63, kg 0..7
            float4 v = {0.f, 0.f, 0.f, 0.f};
            if (m0 + row < M)
                v = *(const float4*)(A + (size_t)(m0 + row) * 160 + k0 + kg * 4);
            At[kg * 4 + 0][row] = v.x;
            At[kg * 4 + 1][row] = v.y;
            At[kg * 4 + 2][row] = v.z;
            At[kg * 4 + 3][row] = v.w;
        }
        __syncthreads();
#pragma unroll 4
        for (int kk = 0; kk < 32; ++kk) {
            float bv0 = Bs[kk][tx], bv1 = Bs[kk][tx + 32], bv2 = Bs[kk][tx + 64],
                  bv3 = Bs[kk][tx + 96], bv4 = Bs[kk][tx + 128];
            float av[16];
#pragma unroll
            for (int jj = 0; jj < 8; ++jj) {
                float2 rd = *(const float2*)&At[kk][ty * 16 + jj * 2];
                av[jj * 2] = rd.x; av[jj * 2 + 1] = rd.y;
            }
#pragma unroll
            for (int r = 0; r < 16; ++r) {
                acc[r][0] = fmaf(av[r], bv0, acc[r][0]);
                acc[r][1] = fmaf(av[r], bv1, acc[r][1]);
                acc[r][2] = fmaf(av[r], bv2, acc[r][2]);
                acc[r][3] = fmaf(av[r], bv3, acc[r][3]);
                acc[r][4] = fmaf(av[r], bv4, acc[r][4]);
            }
        }
        __syncthreads();
    }
    float bv[5] = {0.f, 0.f, 0.f, 0.f, 0.f};
    if (bias) {
        bv[0] = bias[tx]; bv[1] = bias[tx + 32]; bv[2] = bias[tx + 64];
        bv[3] = bias[tx + 96]; bv[4] = bias[tx + 128];
    }
#pragma unroll
    for (int r = 0; r < 16; ++r) {
        int row = m0 + ty * 16 + r;
        if (row < M) {
            float* Cr = C + (size_t)row * 160;
            Cr[tx]       = acc[r][0] + bv[0];
            Cr[tx + 32]  = acc[r][1] + bv[1];
            Cr[tx + 64]  = acc[r][2] + bv[2];
            Cr[tx + 96]  = acc[r][3] + bv[3];
            Cr[tx + 128] = acc[r][4] + bv[4];
        }
    }
}

// ---------------------------------------------------------------------------
// Small GEMM batch: thread-per-(row, 4-col group); everything L1/L2 resident.
// Up to 11 descriptors per launch (one launch per network stage).
// ---------------------------------------------------------------------------
struct SmallDesc {
    const float* A;
    const float* B;
    const float* bias;
    float*       C;
    int M, K, N, ldb, relu;
};
struct SmallBatch { SmallDesc d[11]; };

__global__ __launch_bounds__(256) void gemm_small_batch(SmallBatch sb)
{
    SmallDesc dd = sb.d[blockIdx.y];
    int tid = blockIdx.x * 256 + threadIdx.x;
    int ng = dd.N >> 2;
    int m = tid / ng;
    if (m >= dd.M) return;
    int g = tid - m * ng;
    const float* __restrict__ Ar = dd.A + (size_t)m * dd.K;
    const float* __restrict__ Bp = dd.B + g * 4;
    float4 acc;
    if (dd.bias) acc = *(const float4*)(dd.bias + g * 4);
    else { acc.x = 0.f; acc.y = 0.f; acc.z = 0.f; acc.w = 0.f; }
    for (int k = 0; k < dd.K; ++k) {
        float a = Ar[k];
        float4 b = *(const float4*)(Bp + (size_t)k * dd.ldb);
        acc.x = fmaf(a, b.x, acc.x);
        acc.y = fmaf(a, b.y, acc.y);
        acc.z = fmaf(a, b.z, acc.z);
        acc.w = fmaf(a, b.w, acc.w);
    }
    if (dd.relu) {
        acc.x = fmaxf(acc.x, 0.f); acc.y = fmaxf(acc.y, 0.f);
        acc.z = fmaxf(acc.z, 0.f); acc.w = fmaxf(acc.w, 0.f);
    }
    *(float4*)(dd.C + (size_t)m * dd.N + g * 4) = acc;
}

// ---------------------------------------------------------------------------
// CSR build: count -> exclusive scan (writes rowptr AND resets cnt to cursor)
// -> scatter permutation (uses cnt as cursor)
// ---------------------------------------------------------------------------
__global__ void count_deg(const int* __restrict__ d, int E, int* __restrict__ cnt)
{
    int e = blockIdx.x * 256 + threadIdx.x;
    if (e < E) atomicAdd(&cnt[d[e]], 1);
}

__global__ __launch_bounds__(256) void scan_excl(int* __restrict__ cnt, int* __restrict__ rowptr, int n)
{
    __shared__ int ssum[256];
    int t = threadIdx.x;
    int chunk = (n + 255) / 256;
    int s0 = t * chunk; if (s0 > n) s0 = n;
    int s1 = s0 + chunk; if (s1 > n) s1 = n;
    int local = 0;
    for (int i = s0; i < s1; ++i) local += cnt[i];
    ssum[t] = local;
    __syncthreads();
    if (t == 0) {
        int acc = 0;
        for (int i = 0; i < 256; ++i) { int v = ssum[i]; ssum[i] = acc; acc += v; }
        rowptr[n] = acc;
    }
    __syncthreads();
    int acc = ssum[t];
    for (int i = s0; i < s1; ++i) {
        int v = cnt[i];
        rowptr[i] = acc;
        cnt[i] = acc;       // cnt becomes the scatter cursor
        acc += v;
    }
}

__global__ void scatter_perm(const int* __restrict__ d, int E, int* __restrict__ cursor, int* __restrict__ perm)
{
    int e = blockIdx.x * 256 + threadIdx.x;
    if (e < E) {
        int p = atomicAdd(&cursor[d[e]], 1);
        perm[p] = e;
    }
}

// ---------------------------------------------------------------------------
// Ent-graph aggregation (CSR, no atomics), fused with mean-divide + ReLU.
// Thread = (node, 4-col group); 40 consecutive threads share a node.
// H (inout) already holds ent@WS + bias (from gemm_big).
// ---------------------------------------------------------------------------
__global__ __launch_bounds__(256) void agg_ent_csr(
    const int* __restrict__ rowptr, const int* __restrict__ perm,
    const int* __restrict__ src, const int* __restrict__ e_rel,
    const int* __restrict__ e_time, const int* __restrict__ e_inv,
    const float* __restrict__ arI, const float* __restrict__ arO,
    const float* __restrict__ aeI, const float* __restrict__ aeO,
    const float* __restrict__ atI, const float* __restrict__ atO,
    float* __restrict__ H, int relu)
{
    int tid = blockIdx.x * 256 + threadIdx.x;
    int n = tid / 40;
    if (n >= N_ENT) return;
    int g = tid - n * 40;
    int c = g * 4;
    int b = rowptr[n], e = rowptr[n + 1];
    float ax = 0.f, ay = 0.f, az = 0.f, aw = 0.f;
    for (int j = b; j < e; ++j) {
        int eid = perm[j];
        int inv = e_inv[eid];
        const float* pr = (inv ? arO : arI) + (size_t)e_rel[eid] * 160 + c;
        const float* pe = (inv ? aeO : aeI) + (size_t)src[eid] * 160 + c;
        const float* pt = (inv ? atO : atI) + (size_t)e_time[eid] * 160 + c;
        float4 vr = *(const float4*)pr;
        float4 ve = *(const float4*)pe;
        float4 vt = *(const float4*)pt;
        ax += vr.x + ve.x + vt.x;
        ay += vr.y + ve.y + vt.y;
        az += vr.z + ve.z + vt.z;
        aw += vr.w + ve.w + vt.w;
    }
    size_t idx = (size_t)n * 160 + c;
    float4 h = *(const float4*)(H + idx);
    if (e > b) {
        float s = 1.0f / (float)(e - b);
        h.x = fmaf(ax, s, h.x); h.y = fmaf(ay, s, h.y);
        h.z = fmaf(az, s, h.z); h.w = fmaf(aw, s, h.w);
    }
    if (relu) {
        h.x = fmaxf(h.x, 0.f); h.y = fmaxf(h.y, 0.f);
        h.z = fmaxf(h.z, 0.f); h.w = fmaxf(h.w, 0.f);
    }
    *(float4*)(H + idx) = h;
}

// ---------------------------------------------------------------------------
// Rel-graph aggregation, fully fused: one block per rel node (400 blocks),
// 12 segments x 40 col-groups, LDS partial reduce, no atomics/memset, fused
// mean-divide + ReLU finalize.
// ---------------------------------------------------------------------------
__global__ __launch_bounds__(512) void agg_rel_fused(
    const int* __restrict__ rowptr, const int* __restrict__ perm,
    const int* __restrict__ p_src, const int* __restrict__ p_rel, const int* __restrict__ p_inv,
    const float* __restrict__ bmI, const float* __restrict__ bmO,
    const float* __restrict__ brI, const float* __restrict__ brO,
    float* __restrict__ H, int relu)
{
    __shared__ float part[12][40][4];
    int n = blockIdx.x;
    int t = threadIdx.x;
    int g = t % 40, s = t / 40;
    int b = rowptr[n], e = rowptr[n + 1];
    if (s < 12) {
        int c = g * 4;
        float ax = 0.f, ay = 0.f, az = 0.f, aw = 0.f;
        for (int j = b + s; j < e; j += 12) {
            int eid = perm[j];
            int inv = p_inv[eid];
            const float* pm = (inv ? bmO : bmI) + (size_t)p_rel[eid] * 160 + c;
            const float* pr = (inv ? brO : brI) + (size_t)p_src[eid] * 160 + c;
            float4 vm = *(const float4*)pm;
            float4 vr = *(const float4*)pr;
            ax += vm.x + vr.x; ay += vm.y + vr.y;
            az += vm.z + vr.z; aw += vm.w + vr.w;
        }
        part[s][g][0] = ax; part[s][g][1] = ay;
        part[s][g][2] = az; part[s][g][3] = aw;
    }
    __syncthreads();
    if (t < 160) {
        int gg = t >> 2, q = t & 3;
        float acc = 0.f;
#pragma unroll
        for (int s2 = 0; s2 < 12; ++s2) acc += part[s2][gg][q];
        size_t idx = (size_t)n * 160 + t;
        float h = H[idx];
        int d = e - b;
        if (d > 0) h = fmaf(acc, 1.0f / (float)d, h);
        if (relu) h = fmaxf(h, 0.f);
        H[idx] = h;
    }
}

// z = mean + noise * exp(log_std)
__global__ void sample_k(const float* __restrict__ mean, const float* __restrict__ logstd,
                         const float* __restrict__ noise, float* __restrict__ z, int n)
{
    int i = blockIdx.x * 256 + threadIdx.x;
    if (i < n) z[i] = fmaf(noise[i], expf(logstd[i]), mean[i]);
}

// ---------------------------------------------------------------------------
extern "C" void kernel_launch(void* const* d_in, const int* in_sizes, int n_in,
                              void* d_out, int out_size, void* d_ws, size_t ws_size,
                              hipStream_t stream)
{
    const float* ent0   = (const float*)d_in[0];
    const float* rel0   = (const float*)d_in[1];
    const float* tim0   = (const float*)d_in[2];
    const float* meta0  = (const float*)d_in[3];
    const float* noiseE = (const float*)d_in[4];
    const float* noiseR = (const float*)d_in[5];
    const float* entWI  = (const float*)d_in[6];
    const float* entWIb = (const float*)d_in[7];
    const float* entWO  = (const float*)d_in[8];
    const float* entWOb = (const float*)d_in[9];
    const float* entWS  = (const float*)d_in[10];
    const float* entWSb = (const float*)d_in[11];
    const float* entWT  = (const float*)d_in[12];
    const float* entWTb = (const float*)d_in[13];
    const float* relWI  = (const float*)d_in[14];
    const float* relWIb = (const float*)d_in[15];
    const float* relWO  = (const float*)d_in[16];
    const float* relWOb = (const float*)d_in[17];
    const float* relWS  = (const float*)d_in[18];
    const float* relWSb = (const float*)d_in[19];
    const float* relWM  = (const float*)d_in[20];
    const float* relWMb = (const float*)d_in[21];
    const int* src    = (const int*)d_in[22];
    const int* dst    = (const int*)d_in[23];
    const int* e_rel  = (const int*)d_in[24];
    const int* e_time = (const int*)d_in[25];
    const int* e_inv  = (const int*)d_in[26];
    const int* p_src  = (const int*)d_in[27];
    const int* p_dst  = (const int*)d_in[28];
    const int* p_rel  = (const int*)d_in[29];
    const int* p_inv  = (const int*)d_in[30];

    float* out = (float*)d_out;
    float* OUT_ent   = out + 0;
    float* OUT_ento  = out + 3200000;
    float* OUT_rel   = out + 6400000;
    float* OUT_relo  = out + 6464000;
    float* OUT_tim   = out + 6528000;
    float* OUT_timo  = out + 6557280;
    float* OUT_meta  = out + 6586560;
    float* OUT_metao = out + 6714560;

    // ---- workspace carve-out (~57 MB, within proven budget) ----
    char* wsp = (char*)d_ws;
    size_t off = 0;
    auto allocF = [&](size_t n) -> float* {
        float* p = (float*)(wsp + off);
        off += ((n * sizeof(float) + 255) & ~(size_t)255);
        return p;
    };
    auto allocI = [&](size_t n) -> int* {
        int* p = (int*)(wsp + off);
        off += ((n * sizeof(int) + 255) & ~(size_t)255);
        return p;
    };
    float* AI      = allocF(3200000);   // ent-part WI precompute
    float* AO      = allocF(3200000);   // ent-part WO precompute
    float* B1v     = allocF(3200000);   // ent1 / logstd_e / ent_o1
    float* B5v     = allocF(3200000);   // mean_e / z_e
    float* tim1    = allocF(29280);
    float* tim_o1  = allocF(29280);
    float* rel1    = allocF(64000);
    float* rel_o1  = allocF(64000);
    float* meta1   = allocF(128000);
    float* meta_o1 = allocF(128000);
    float* arI     = allocF(64000);     // rel-part precompute (+bias) for ent layer
    float* arO     = allocF(64000);
    float* atI     = allocF(58560);     // time-part precompute for ent layer
    float* atO     = allocF(58560);
    float* bmI     = allocF(128000);    // meta-part precompute (+bias) for rel layer
    float* bmO     = allocF(128000);
    float* brI     = allocF(64000);     // rel-part precompute for rel layer
    float* brO     = allocF(64000);
    float* meanR   = allocF(64000);
    float* logstdR = allocF(64000);
    float* zR      = allocF(64000);
    int* cntE    = allocI(N_ENT);       // becomes cursor after scan
    int* rowptrE = allocI(N_ENT + 1);
    int* permE   = allocI(NE);
    int* cntR    = allocI(N_RELN);
    int* rowptrR = allocI(N_RELN + 1);
    int* permR   = allocI(NPE);
    if (ws_size < off) return;  // loud failure rather than silent corruption

    // ---- CSR build ----
    hipMemsetAsync(cntE, 0, N_ENT * sizeof(int), stream);
    hipMemsetAsync(cntR, 0, N_RELN * sizeof(int), stream);
    count_deg<<<(NE + 255) / 256, 256, 0, stream>>>(dst, NE, cntE);
    count_deg<<<(NPE + 255) / 256, 256, 0, stream>>>(p_dst, NPE, cntR);
    scan_excl<<<1, 256, 0, stream>>>(cntE, rowptrE, N_ENT);
    scan_excl<<<1, 256, 0, stream>>>(cntR, rowptrR, N_RELN);
    scatter_perm<<<(NE + 255) / 256, 256, 0, stream>>>(dst, NE, cntE, permE);
    scatter_perm<<<(NPE + 255) / 256, 256, 0, stream>>>(p_dst, NPE, cntR, permR);

    // ---- one network stage: ent layer + rel layer (merged launches) ----
    // ent W layout: WI/WO [li][400][160]; rows 0-159 rel-part, 160-319
    // ent-part, 320-399 time-part. rel W: [li][320][160]; rows 0-159
    // meta-part, 160-319 rel-part.
    auto stage = [&](int li, const float* entIn, const float* relIn, const float* timIn,
                     const float* metaIn, float* entOut, float* timOut,
                     float* relOut, float* metaOut, int act) {
        const float* WI  = entWI + (size_t)li * 64000;
        const float* WO  = entWO + (size_t)li * 64000;
        const float* rWI = relWI + (size_t)li * 51200;
        const float* rWO = relWO + (size_t)li * 51200;

        SmallBatch sb{};
        int ns = 0;
        sb.d[ns++] = SmallDesc{relIn,  WI,          entWIb + li * 160, arI,    N_RELN, 160, 160, 160, 0};
        sb.d[ns++] = SmallDesc{relIn,  WO,          entWOb + li * 160, arO,    N_RELN, 160, 160, 160, 0};
        sb.d[ns++] = SmallDesc{timIn,  WI + 51200,  nullptr,           atI,    N_TIME,  80, 160, 160, 0};
        sb.d[ns++] = SmallDesc{timIn,  WO + 51200,  nullptr,           atO,    N_TIME,  80, 160, 160, 0};
        if (timOut)
            sb.d[ns++] = SmallDesc{timIn, entWT + (size_t)li * 6400, entWTb + li * 80,
                                   timOut, N_TIME, 80, 80, 80, act};
        sb.d[ns++] = SmallDesc{metaIn, rWI,         relWIb + li * 160, bmI,    N_META, 160, 160, 160, 0};
        sb.d[ns++] = SmallDesc{metaIn, rWO,         relWOb + li * 160, bmO,    N_META, 160, 160, 160, 0};
        sb.d[ns++] = SmallDesc{relIn,  rWI + 25600, nullptr,           brI,    N_RELN, 160, 160, 160, 0};
        sb.d[ns++] = SmallDesc{relIn,  rWO + 25600, nullptr,           brO,    N_RELN, 160, 160, 160, 0};
        sb.d[ns++] = SmallDesc{relIn,  relWS + (size_t)li * 25600, relWSb + li * 160,
                               relOut, N_RELN, 160, 160, 160, 0};
        if (metaOut)
            sb.d[ns++] = SmallDesc{metaIn, relWM + (size_t)li * 25600, relWMb + li * 160,
                                   metaOut, N_META, 160, 160, 160, act};
        gemm_small_batch<<<dim3(125, ns), 256, 0, stream>>>(sb);

        BigBatch bbatch;
        bbatch.B[0] = WI + 25600;                  bbatch.bias[0] = nullptr;             bbatch.C[0] = AI;
        bbatch.B[1] = WO + 25600;                  bbatch.bias[1] = nullptr;             bbatch.C[1] = AO;
        bbatch.B[2] = entWS + (size_t)li * 25600;  bbatch.bias[2] = entWSb + li * 160;   bbatch.C[2] = entOut;
        gemm_big<<<dim3(313, 1, 3), 128, 0, stream>>>(entIn, N_ENT, bbatch);

        agg_ent_csr<<<(N_ENT * 40 + 255) / 256, 256, 0, stream>>>(
            rowptrE, permE, src, e_rel, e_time, e_inv, arI, arO, AI, AO, atI, atO, entOut, act);
        agg_rel_fused<<<N_RELN, 512, 0, stream>>>(
            rowptrR, permR, p_src, p_rel, p_inv, bmI, bmO, brI, brO, relOut, act);
    };

    // ---- encoder ----
    stage(0, ent0, rel0, tim0, meta0, B1v, tim1, rel1, meta1, 1);
    stage(1, B1v, rel1, tim1, meta1, OUT_ent, OUT_tim, OUT_rel, OUT_meta, 0);
    // ---- variational heads (4=mean, 5=log_std) ----
    stage(4, OUT_ent, OUT_rel, OUT_tim, OUT_meta, B5v, nullptr, meanR, nullptr, 0);
    stage(5, OUT_ent, OUT_rel, OUT_tim, OUT_meta, B1v, nullptr, logstdR, nullptr, 0);
    sample_k<<<(3200000 + 255) / 256, 256, 0, stream>>>(B5v, B1v, noiseE, B5v, 3200000); // z_e
    sample_k<<<(64000 + 255) / 256, 256, 0, stream>>>(meanR, logstdR, noiseR, zR, 64000); // z_r
    // ---- decoder (layers 2,3) ----
    stage(2, B5v, zR, OUT_tim, OUT_meta, B1v, tim_o1, rel_o1, meta_o1, 1);
    stage(3, B1v, rel_o1, tim_o1, meta_o1, OUT_ento, OUT_timo, OUT_relo, OUT_metao, 0);
}

// Round 3
// 1030.302 us; speedup vs baseline: 1.7613x; 1.4724x over previous
//
#include <hip/hip_runtime.h>
#include <math.h>

#define N_ENT     20000
#define N_RELN    400
#define N_TIME    366
#define N_META    800
#define NE        200000
#define NPE       80000
// dims: ENT=160, REL=160, TIME=80; DIN_E=400, DIN_R=320; NL=6

typedef __attribute__((ext_vector_type(8))) short short8;
typedef __attribute__((ext_vector_type(4))) float f32x4;

static __device__ __forceinline__ ushort f2bf(float x) {
    unsigned u = __float_as_uint(x);
    unsigned r = (u + 0x7FFF + ((u >> 16) & 1)) >> 16;   // RN-to-even
    return (ushort)r;
}
static __device__ __forceinline__ float bf2f(ushort b) {
    return __uint_as_float(((unsigned)b) << 16);
}

// ---------------------------------------------------------------------------
// Weight prep: 18 big 160x160 matrices -> transposed [col][k] bf16 hi/lo.
// ---------------------------------------------------------------------------
struct BPrep { const float* W[18]; };

__global__ __launch_bounds__(256) void bprep(BPrep bp, ushort* __restrict__ hi, ushort* __restrict__ lo)
{
    int idx = blockIdx.x * 256 + threadIdx.x;       // (s, n, kc): 18*160*20
    if (idx >= 18 * 160 * 20) return;
    int s = idx / 3200, rem = idx - s * 3200;
    int n = rem / 20, kc = rem - n * 20;
    const float* __restrict__ W = bp.W[s];
    ushort h[8], l[8];
#pragma unroll
    for (int j = 0; j < 8; ++j) {
        float x = W[(kc * 8 + j) * 160 + n];
        h[j] = f2bf(x);
        l[j] = f2bf(x - bf2f(h[j]));
    }
    size_t o = (size_t)s * 25600 + n * 160 + kc * 8;
    *(short8*)(hi + o) = *(short8*)h;
    *(short8*)(lo + o) = *(short8*)l;
}

// Activation split: f32 [M][160] -> bf16 hi/lo
__global__ __launch_bounds__(256) void aprep(const float* __restrict__ in,
                                             ushort* __restrict__ hi, ushort* __restrict__ lo, int n8)
{
    int i = blockIdx.x * 256 + threadIdx.x;
    if (i >= n8) return;
    const float* p = in + (size_t)i * 8;
    ushort h[8], l[8];
#pragma unroll
    for (int j = 0; j < 8; ++j) {
        float x = p[j];
        h[j] = f2bf(x);
        l[j] = f2bf(x - bf2f(h[j]));
    }
    *(short8*)(hi + (size_t)i * 8) = *(short8*)h;
    *(short8*)(lo + (size_t)i * 8) = *(short8*)l;
}

// ---------------------------------------------------------------------------
// Big GEMM v3 (MFMA split-bf16): C[M,160] = A[M,160]@B[160,160] (+bias).
// 256 thr = 4 waves; BM=64 (wave w -> rows w*16..+15); 10 col-tiles of 16;
// BK=32, 5 k-iters. 3 mfma (hh, lh, hl) per tile per iter.
// LDS rows padded to 40 ushorts (80B): bank = (20r+4q)%32 -> 2-way max.
// k-map per lane: k = (lane>>4)*8 + j, applied identically to A and B
// (permutation-safe). C/D: col=lane&15, row=(lane>>4)*4+reg [m89].
// ---------------------------------------------------------------------------
struct BigMF {
    const ushort* bh[3];
    const ushort* bl[3];
    const float*  bias[3];
    float*        C[3];
};

__global__ __launch_bounds__(256, 4) void gemm_big_mfma(
    const ushort* __restrict__ Ah, const ushort* __restrict__ Al, int M, BigMF bb)
{
    __shared__ ushort Ahi[64][40], Alo[64][40];
    __shared__ ushort Bhi[160][40], Blo[160][40];
    const int z = blockIdx.z;
    const ushort* __restrict__ Bh = bb.bh[z];
    const ushort* __restrict__ Bl = bb.bl[z];
    const float*  __restrict__ bias = bb.bias[z];
    float* __restrict__ C = bb.C[z];
    const int m0 = blockIdx.x * 64;
    const int t  = threadIdx.x;
    const int lane = t & 63, w = t >> 6;
    const int fr = lane & 15, fq = lane >> 4;

    f32x4 acc[10];
#pragma unroll
    for (int i = 0; i < 10; ++i) acc[i] = (f32x4){0.f, 0.f, 0.f, 0.f};

    for (int k0 = 0; k0 < 160; k0 += 32) {
        // stage A: 64 rows x 4 kchunks(8) -> 256 chunks, 1/thread
        {
            int r = t >> 2, kc = t & 3;
            int row = m0 + r;
            short8 vh = {0,0,0,0,0,0,0,0}, vl = {0,0,0,0,0,0,0,0};
            if (row < M) {
                size_t o = (size_t)row * 160 + k0 + kc * 8;
                vh = *(const short8*)(Ah + o);
                vl = *(const short8*)(Al + o);
            }
            *(short8*)&Ahi[r][kc * 8] = vh;
            *(short8*)&Alo[r][kc * 8] = vl;
        }
        // stage B: 160 cols x 4 kchunks = 640 chunks
#pragma unroll
        for (int i = 0; i < 3; ++i) {
            int idx = t + i * 256;
            if (idx < 640) {
                int col = idx >> 2, kc = idx & 3;
                size_t o = (size_t)col * 160 + k0 + kc * 8;
                *(short8*)&Bhi[col][kc * 8] = *(const short8*)(Bh + o);
                *(short8*)&Blo[col][kc * 8] = *(const short8*)(Bl + o);
            }
        }
        __syncthreads();
        short8 ah = *(const short8*)&Ahi[w * 16 + fr][fq * 8];
        short8 al = *(const short8*)&Alo[w * 16 + fr][fq * 8];
#pragma unroll
        for (int tt = 0; tt < 10; ++tt) {
            short8 bh = *(const short8*)&Bhi[tt * 16 + fr][fq * 8];
            short8 bl = *(const short8*)&Blo[tt * 16 + fr][fq * 8];
            acc[tt] = __builtin_amdgcn_mfma_f32_16x16x32_bf16(ah, bh, acc[tt], 0, 0, 0);
            acc[tt] = __builtin_amdgcn_mfma_f32_16x16x32_bf16(al, bh, acc[tt], 0, 0, 0);
            acc[tt] = __builtin_amdgcn_mfma_f32_16x16x32_bf16(ah, bl, acc[tt], 0, 0, 0);
        }
        __syncthreads();
    }
    // epilogue: bias + store. row = m0 + w*16 + fq*4 + q, col = tt*16 + fr
#pragma unroll
    for (int tt = 0; tt < 10; ++tt) {
        int col = tt * 16 + fr;
        float bv = bias ? bias[col] : 0.f;
#pragma unroll
        for (int q = 0; q < 4; ++q) {
            int row = m0 + w * 16 + fq * 4 + q;
            if (row < M) C[(size_t)row * 160 + col] = acc[tt][q] + bv;
        }
    }
}

// ---------------------------------------------------------------------------
// Small GEMM batch (f32): thread-per-(row, 4-col group); L2-resident.
// ---------------------------------------------------------------------------
struct SmallDesc {
    const float* A;
    const float* B;
    const float* bias;
    float*       C;
    int M, K, N, ldb, relu;
};
struct SmallBatch { SmallDesc d[18]; };

__global__ __launch_bounds__(256) void gemm_small_batch(SmallBatch sb)
{
    SmallDesc dd = sb.d[blockIdx.y];
    int tid = blockIdx.x * 256 + threadIdx.x;
    int ng = dd.N >> 2;
    int m = tid / ng;
    if (m >= dd.M) return;
    int g = tid - m * ng;
    const float* __restrict__ Ar = dd.A + (size_t)m * dd.K;
    const float* __restrict__ Bp = dd.B + g * 4;
    float4 acc;
    if (dd.bias) acc = *(const float4*)(dd.bias + g * 4);
    else { acc.x = 0.f; acc.y = 0.f; acc.z = 0.f; acc.w = 0.f; }
    for (int k = 0; k < dd.K; ++k) {
        float a = Ar[k];
        float4 b = *(const float4*)(Bp + (size_t)k * dd.ldb);
        acc.x = fmaf(a, b.x, acc.x);
        acc.y = fmaf(a, b.y, acc.y);
        acc.z = fmaf(a, b.z, acc.z);
        acc.w = fmaf(a, b.w, acc.w);
    }
    if (dd.relu) {
        acc.x = fmaxf(acc.x, 0.f); acc.y = fmaxf(acc.y, 0.f);
        acc.z = fmaxf(acc.z, 0.f); acc.w = fmaxf(acc.w, 0.f);
    }
    *(float4*)(dd.C + (size_t)m * dd.N + g * 4) = acc;
}

// ---------------------------------------------------------------------------
// CSR build with packed edge payload {i0, i1, i2, inv}.
// ---------------------------------------------------------------------------
__global__ void count_deg(const int* __restrict__ d, int E, int* __restrict__ cnt)
{
    int e = blockIdx.x * 256 + threadIdx.x;
    if (e < E) atomicAdd(&cnt[d[e]], 1);
}

__global__ __launch_bounds__(256) void scan_excl(int* __restrict__ cnt, int* __restrict__ rowptr, int n)
{
    __shared__ int ssum[256];
    int t = threadIdx.x;
    int chunk = (n + 255) / 256;
    int s0 = t * chunk; if (s0 > n) s0 = n;
    int s1 = s0 + chunk; if (s1 > n) s1 = n;
    int local = 0;
    for (int i = s0; i < s1; ++i) local += cnt[i];
    ssum[t] = local;
    __syncthreads();
    if (t == 0) {
        int acc = 0;
        for (int i = 0; i < 256; ++i) { int v = ssum[i]; ssum[i] = acc; acc += v; }
        rowptr[n] = acc;
    }
    __syncthreads();
    int acc = ssum[t];
    for (int i = s0; i < s1; ++i) {
        int v = cnt[i];
        rowptr[i] = acc;
        cnt[i] = acc;       // cnt becomes scatter cursor
        acc += v;
    }
}

__global__ void scatter_pack(const int* __restrict__ d, const int* __restrict__ a0,
                             const int* __restrict__ a1, const int* __restrict__ a2,
                             const int* __restrict__ inv, int E,
                             int* __restrict__ cursor, int4* __restrict__ pack)
{
    int e = blockIdx.x * 256 + threadIdx.x;
    if (e < E) {
        int p = atomicAdd(&cursor[d[e]], 1);
        int4 v;
        v.x = a0[e]; v.y = a1[e]; v.z = a2 ? a2[e] : 0; v.w = inv[e];
        pack[p] = v;
    }
}

// ---------------------------------------------------------------------------
// Ent aggregation (CSR, no atomics) + mean + ReLU. 40 thr/node, int4 payload.
// ---------------------------------------------------------------------------
__global__ __launch_bounds__(256) void agg_ent_csr(
    const int* __restrict__ rowptr, const int4* __restrict__ pack,
    const float* __restrict__ arI, const float* __restrict__ arO,
    const float* __restrict__ aeI, const float* __restrict__ aeO,
    const float* __restrict__ atI, const float* __restrict__ atO,
    float* __restrict__ H, int relu)
{
    int tid = blockIdx.x * 256 + threadIdx.x;
    int n = tid / 40;
    if (n >= N_ENT) return;
    int g = tid - n * 40;
    int c = g * 4;
    int b = rowptr[n], e = rowptr[n + 1];
    float ax = 0.f, ay = 0.f, az = 0.f, aw = 0.f;
    for (int j = b; j < e; ++j) {
        int4 p = pack[j];
        const float* t1 = (p.w ? arO : arI) + (size_t)p.x * 160 + c;
        const float* t2 = (p.w ? aeO : aeI) + (size_t)p.y * 160 + c;
        const float* t3 = (p.w ? atO : atI) + (size_t)p.z * 160 + c;
        float4 v1 = *(const float4*)t1;
        float4 v2 = *(const float4*)t2;
        float4 v3 = *(const float4*)t3;
        ax += v1.x + v2.x + v3.x;
        ay += v1.y + v2.y + v3.y;
        az += v1.z + v2.z + v3.z;
        aw += v1.w + v2.w + v3.w;
    }
    size_t idx = (size_t)n * 160 + c;
    float4 h = *(const float4*)(H + idx);
    if (e > b) {
        float s = 1.0f / (float)(e - b);
        h.x = fmaf(ax, s, h.x); h.y = fmaf(ay, s, h.y);
        h.z = fmaf(az, s, h.z); h.w = fmaf(aw, s, h.w);
    }
    if (relu) {
        h.x = fmaxf(h.x, 0.f); h.y = fmaxf(h.y, 0.f);
        h.z = fmaxf(h.z, 0.f); h.w = fmaxf(h.w, 0.f);
    }
    *(float4*)(H + idx) = h;
}

// Head-5 variant: logstd = Hs + agg/deg; out = mean + noise*exp(logstd)
__global__ __launch_bounds__(256) void agg_ent_sample(
    const int* __restrict__ rowptr, const int4* __restrict__ pack,
    const float* __restrict__ arI, const float* __restrict__ arO,
    const float* __restrict__ aeI, const float* __restrict__ aeO,
    const float* __restrict__ atI, const float* __restrict__ atO,
    const float* __restrict__ Hs, const float* __restrict__ mean,
    const float* __restrict__ noise, float* __restrict__ out)
{
    int tid = blockIdx.x * 256 + threadIdx.x;
    int n = tid / 40;
    if (n >= N_ENT) return;
    int g = tid - n * 40;
    int c = g * 4;
    int b = rowptr[n], e = rowptr[n + 1];
    float ax = 0.f, ay = 0.f, az = 0.f, aw = 0.f;
    for (int j = b; j < e; ++j) {
        int4 p = pack[j];
        const float* t1 = (p.w ? arO : arI) + (size_t)p.x * 160 + c;
        const float* t2 = (p.w ? aeO : aeI) + (size_t)p.y * 160 + c;
        const float* t3 = (p.w ? atO : atI) + (size_t)p.z * 160 + c;
        float4 v1 = *(const float4*)t1;
        float4 v2 = *(const float4*)t2;
        float4 v3 = *(const float4*)t3;
        ax += v1.x + v2.x + v3.x;
        ay += v1.y + v2.y + v3.y;
        az += v1.z + v2.z + v3.z;
        aw += v1.w + v2.w + v3.w;
    }
    size_t idx = (size_t)n * 160 + c;
    float4 h = *(const float4*)(Hs + idx);
    if (e > b) {
        float s = 1.0f / (float)(e - b);
        h.x = fmaf(ax, s, h.x); h.y = fmaf(ay, s, h.y);
        h.z = fmaf(az, s, h.z); h.w = fmaf(aw, s, h.w);
    }
    float4 mn = *(const float4*)(mean + idx);
    float4 nz = *(const float4*)(noise + idx);
    float4 zv;
    zv.x = fmaf(nz.x, expf(h.x), mn.x);
    zv.y = fmaf(nz.y, expf(h.y), mn.y);
    zv.z = fmaf(nz.z, expf(h.z), mn.z);
    zv.w = fmaf(nz.w, expf(h.w), mn.w);
    *(float4*)(out + idx) = zv;
}

// ---------------------------------------------------------------------------
// Rel aggregation: block per node, 12 segments x 40 col-groups, LDS reduce.
// ---------------------------------------------------------------------------
__global__ __launch_bounds__(512) void agg_rel_fused(
    const int* __restrict__ rowptr, const int4* __restrict__ pack,
    const float* __restrict__ bmI, const float* __restrict__ bmO,
    const float* __restrict__ brI, const float* __restrict__ brO,
    float* __restrict__ H, int relu)
{
    __shared__ float part[12][40][4];
    int n = blockIdx.x;
    int t = threadIdx.x;
    int g = t % 40, s = t / 40;
    int b = rowptr[n], e = rowptr[n + 1];
    if (s < 12) {
        int c = g * 4;
        float ax = 0.f, ay = 0.f, az = 0.f, aw = 0.f;
        for (int j = b + s; j < e; j += 12) {
            int4 p = pack[j];
            const float* pm = (p.w ? bmO : bmI) + (size_t)p.x * 160 + c;
            const float* pr = (p.w ? brO : brI) + (size_t)p.y * 160 + c;
            float4 vm = *(const float4*)pm;
            float4 vr = *(const float4*)pr;
            ax += vm.x + vr.x; ay += vm.y + vr.y;
            az += vm.z + vr.z; aw += vm.w + vr.w;
        }
        part[s][g][0] = ax; part[s][g][1] = ay;
        part[s][g][2] = az; part[s][g][3] = aw;
    }
    __syncthreads();
    if (t < 160) {
        int gg = t >> 2, q = t & 3;
        float acc = 0.f;
#pragma unroll
        for (int s2 = 0; s2 < 12; ++s2) acc += part[s2][gg][q];
        size_t idx = (size_t)n * 160 + t;
        float h = H[idx];
        int d = e - b;
        if (d > 0) h = fmaf(acc, 1.0f / (float)d, h);
        if (relu) h = fmaxf(h, 0.f);
        H[idx] = h;
    }
}

__global__ __launch_bounds__(512) void agg_rel_sample(
    const int* __restrict__ rowptr, const int4* __restrict__ pack,
    const float* __restrict__ bmI, const float* __restrict__ bmO,
    const float* __restrict__ brI, const float* __restrict__ brO,
    const float* __restrict__ Hs, const float* __restrict__ mean,
    const float* __restrict__ noise, float* __restrict__ out)
{
    __shared__ float part[12][40][4];
    int n = blockIdx.x;
    int t = threadIdx.x;
    int g = t % 40, s = t / 40;
    int b = rowptr[n], e = rowptr[n + 1];
    if (s < 12) {
        int c = g * 4;
        float ax = 0.f, ay = 0.f, az = 0.f, aw = 0.f;
        for (int j = b + s; j < e; j += 12) {
            int4 p = pack[j];
            const float* pm = (p.w ? bmO : bmI) + (size_t)p.x * 160 + c;
            const float* pr = (p.w ? brO : brI) + (size_t)p.y * 160 + c;
            float4 vm = *(const float4*)pm;
            float4 vr = *(const float4*)pr;
            ax += vm.x + vr.x; ay += vm.y + vr.y;
            az += vm.z + vr.z; aw += vm.w + vr.w;
        }
        part[s][g][0] = ax; part[s][g][1] = ay;
        part[s][g][2] = az; part[s][g][3] = aw;
    }
    __syncthreads();
    if (t < 160) {
        int gg = t >> 2, q = t & 3;
        float acc = 0.f;
#pragma unroll
        for (int s2 = 0; s2 < 12; ++s2) acc += part[s2][gg][q];
        size_t idx = (size_t)n * 160 + t;
        float h = Hs[idx];
        int d = e - b;
        if (d > 0) h = fmaf(acc, 1.0f / (float)d, h);
        out[idx] = fmaf(noise[idx], expf(h), mean[idx]);
    }
}

// ---------------------------------------------------------------------------
extern "C" void kernel_launch(void* const* d_in, const int* in_sizes, int n_in,
                              void* d_out, int out_size, void* d_ws, size_t ws_size,
                              hipStream_t stream)
{
    const float* ent0   = (const float*)d_in[0];
    const float* rel0   = (const float*)d_in[1];
    const float* tim0   = (const float*)d_in[2];
    const float* meta0  = (const float*)d_in[3];
    const float* noiseE = (const float*)d_in[4];
    const float* noiseR = (const float*)d_in[5];
    const float* entWI  = (const float*)d_in[6];
    const float* entWIb = (const float*)d_in[7];
    const float* entWO  = (const float*)d_in[8];
    const float* entWOb = (const float*)d_in[9];
    const float* entWS  = (const float*)d_in[10];
    const float* entWSb = (const float*)d_in[11];
    const float* entWT  = (const float*)d_in[12];
    const float* entWTb = (const float*)d_in[13];
    const float* relWI  = (const float*)d_in[14];
    const float* relWIb = (const float*)d_in[15];
    const float* relWO  = (const float*)d_in[16];
    const float* relWOb = (const float*)d_in[17];
    const float* relWS  = (const float*)d_in[18];
    const float* relWSb = (const float*)d_in[19];
    const float* relWM  = (const float*)d_in[20];
    const float* relWMb = (const float*)d_in[21];
    const int* src    = (const int*)d_in[22];
    const int* dst    = (const int*)d_in[23];
    const int* e_rel  = (const int*)d_in[24];
    const int* e_time = (const int*)d_in[25];
    const int* e_inv  = (const int*)d_in[26];
    const int* p_src  = (const int*)d_in[27];
    const int* p_dst  = (const int*)d_in[28];
    const int* p_rel  = (const int*)d_in[29];
    const int* p_inv  = (const int*)d_in[30];

    float* out = (float*)d_out;
    float* OUT_ent   = out + 0;
    float* OUT_ento  = out + 3200000;
    float* OUT_rel   = out + 6400000;
    float* OUT_relo  = out + 6464000;
    float* OUT_tim   = out + 6528000;
    float* OUT_timo  = out + 6557280;
    float* OUT_meta  = out + 6586560;
    float* OUT_metao = out + 6714560;

    // ---- workspace carve-out (~76 MB) ----
    char* wsp = (char*)d_ws;
    size_t off = 0;
    auto allocF = [&](size_t n) -> float* {
        float* p = (float*)(wsp + off);
        off += ((n * sizeof(float) + 255) & ~(size_t)255);
        return p;
    };
    auto allocU = [&](size_t n) -> ushort* {
        ushort* p = (ushort*)(wsp + off);
        off += ((n * sizeof(ushort) + 255) & ~(size_t)255);
        return p;
    };
    auto allocI = [&](size_t n) -> int* {
        int* p = (int*)(wsp + off);
        off += ((n * sizeof(int) + 255) & ~(size_t)255);
        return p;
    };
    float* AI      = allocF(3200000);
    float* AO      = allocF(3200000);
    float* B1v     = allocF(3200000);   // ent1 / Hs(logstd_e) / ent_o1
    float* B5v     = allocF(3200000);   // mean_e / z_e
    float* tim1    = allocF(29280);
    float* tim_o1  = allocF(29280);
    float* rel1    = allocF(64000);
    float* rel_o1  = allocF(64000);
    float* meta1   = allocF(128000);
    float* meta_o1 = allocF(128000);
    float* arI  = allocF(64000);
    float* arO  = allocF(64000);
    float* atI  = allocF(58560);
    float* atO  = allocF(58560);
    float* bmI  = allocF(128000);
    float* bmO  = allocF(128000);
    float* brI  = allocF(64000);
    float* brO  = allocF(64000);
    float* ar5I = allocF(64000);
    float* ar5O = allocF(64000);
    float* at5I = allocF(58560);
    float* at5O = allocF(58560);
    float* bm5I = allocF(128000);
    float* bm5O = allocF(128000);
    float* br5I = allocF(64000);
    float* br5O = allocF(64000);
    float* hR4  = allocF(64000);        // mean_r
    float* hR5  = allocF(64000);        // Hs for rel logstd
    float* zR   = allocF(64000);
    ushort* Ahg = allocU(3200000);      // activation hi
    ushort* Alg = allocU(3200000);      // activation lo
    ushort* Bhg = allocU(18 * 25600);   // weight hi (transposed)
    ushort* Blg = allocU(18 * 25600);
    int*  cntE    = allocI(N_ENT);
    int*  rowptrE = allocI(N_ENT + 1);
    int4* packE   = (int4*)allocI(NE * 4);
    int*  cntR    = allocI(N_RELN);
    int*  rowptrR = allocI(N_RELN + 1);
    int4* packR   = (int4*)allocI(NPE * 4);
    if (ws_size < off) return;  // loud failure (output stays poisoned)

    // ---- CSR build + packed payloads ----
    hipMemsetAsync(cntE, 0, N_ENT * sizeof(int), stream);
    hipMemsetAsync(cntR, 0, N_RELN * sizeof(int), stream);
    count_deg<<<(NE + 255) / 256, 256, 0, stream>>>(dst, NE, cntE);
    count_deg<<<(NPE + 255) / 256, 256, 0, stream>>>(p_dst, NPE, cntR);
    scan_excl<<<1, 256, 0, stream>>>(cntE, rowptrE, N_ENT);
    scan_excl<<<1, 256, 0, stream>>>(cntR, rowptrR, N_RELN);
    scatter_pack<<<(NE + 255) / 256, 256, 0, stream>>>(dst, e_rel, src, e_time, e_inv, NE, cntE, packE);
    scatter_pack<<<(NPE + 255) / 256, 256, 0, stream>>>(p_dst, p_rel, p_src, nullptr, p_inv, NPE, cntR, packR);

    // ---- weight prep: slots li*3 + {0:WIent, 1:WOent, 2:WS} ----
    BPrep bp;
    for (int li = 0; li < 6; ++li) {
        bp.W[li * 3 + 0] = entWI + (size_t)li * 64000 + 25600;
        bp.W[li * 3 + 1] = entWO + (size_t)li * 64000 + 25600;
        bp.W[li * 3 + 2] = entWS + (size_t)li * 25600;
    }
    bprep<<<(18 * 160 * 20 + 255) / 256, 256, 0, stream>>>(bp, Bhg, Blg);

    auto big3 = [&](int li, float* entOut) {
        BigMF bb;
        for (int j = 0; j < 3; ++j) {
            bb.bh[j] = Bhg + (size_t)(li * 3 + j) * 25600;
            bb.bl[j] = Blg + (size_t)(li * 3 + j) * 25600;
        }
        bb.bias[0] = nullptr; bb.bias[1] = nullptr; bb.bias[2] = entWSb + li * 160;
        bb.C[0] = AI; bb.C[1] = AO; bb.C[2] = entOut;
        gemm_big_mfma<<<dim3(313, 1, 3), 256, 0, stream>>>(Ahg, Alg, N_ENT, bb);
    };
    auto prepA = [&](const float* entIn) {
        aprep<<<(400000 + 255) / 256, 256, 0, stream>>>(entIn, Ahg, Alg, 400000);
    };

    // ---- normal stage (li in {0,1,2,3}) ----
    auto stage = [&](int li, const float* entIn, const float* relIn, const float* timIn,
                     const float* metaIn, float* entOut, float* timOut,
                     float* relOut, float* metaOut, int act) {
        const float* WI  = entWI + (size_t)li * 64000;
        const float* WO  = entWO + (size_t)li * 64000;
        const float* rWI = relWI + (size_t)li * 51200;
        const float* rWO = relWO + (size_t)li * 51200;

        SmallBatch sb{};
        int ns = 0;
        sb.d[ns++] = SmallDesc{relIn,  WI,          entWIb + li * 160, arI,    N_RELN, 160, 160, 160, 0};
        sb.d[ns++] = SmallDesc{relIn,  WO,          entWOb + li * 160, arO,    N_RELN, 160, 160, 160, 0};
        sb.d[ns++] = SmallDesc{timIn,  WI + 51200,  nullptr,           atI,    N_TIME,  80, 160, 160, 0};
        sb.d[ns++] = SmallDesc{timIn,  WO + 51200,  nullptr,           atO,    N_TIME,  80, 160, 160, 0};
        if (timOut)
            sb.d[ns++] = SmallDesc{timIn, entWT + (size_t)li * 6400, entWTb + li * 80,
                                   timOut, N_TIME, 80, 80, 80, act};
        sb.d[ns++] = SmallDesc{metaIn, rWI,         relWIb + li * 160, bmI,    N_META, 160, 160, 160, 0};
        sb.d[ns++] = SmallDesc{metaIn, rWO,         relWOb + li * 160, bmO,    N_META, 160, 160, 160, 0};
        sb.d[ns++] = SmallDesc{relIn,  rWI + 25600, nullptr,           brI,    N_RELN, 160, 160, 160, 0};
        sb.d[ns++] = SmallDesc{relIn,  rWO + 25600, nullptr,           brO,    N_RELN, 160, 160, 160, 0};
        sb.d[ns++] = SmallDesc{relIn,  relWS + (size_t)li * 25600, relWSb + li * 160,
                               relOut, N_RELN, 160, 160, 160, 0};
        if (metaOut)
            sb.d[ns++] = SmallDesc{metaIn, relWM + (size_t)li * 25600, relWMb + li * 160,
                                   metaOut, N_META, 160, 160, 160, act};
        gemm_small_batch<<<dim3(125, ns), 256, 0, stream>>>(sb);

        prepA(entIn);
        big3(li, entOut);
        agg_ent_csr<<<(N_ENT * 40 + 255) / 256, 256, 0, stream>>>(
            rowptrE, packE, arI, arO, AI, AO, atI, atO, entOut, act);
        agg_rel_fused<<<N_RELN, 512, 0, stream>>>(
            rowptrR, packR, bmI, bmO, brI, brO, relOut, act);
    };

    // ---- encoder ----
    stage(0, ent0, rel0, tim0, meta0, B1v, tim1, rel1, meta1, 1);
    stage(1, B1v, rel1, tim1, meta1, OUT_ent, OUT_tim, OUT_rel, OUT_meta, 0);

    // ---- variational heads (li=4 mean, li=5 log_std), fused sampling ----
    {
        const float* WI4  = entWI + (size_t)4 * 64000;
        const float* WO4  = entWO + (size_t)4 * 64000;
        const float* WI5  = entWI + (size_t)5 * 64000;
        const float* WO5  = entWO + (size_t)5 * 64000;
        const float* rWI4 = relWI + (size_t)4 * 51200;
        const float* rWO4 = relWO + (size_t)4 * 51200;
        const float* rWI5 = relWI + (size_t)5 * 51200;
        const float* rWO5 = relWO + (size_t)5 * 51200;

        SmallBatch sb{};
        int ns = 0;
        sb.d[ns++] = SmallDesc{OUT_rel,  WI4,          entWIb + 4 * 160, arI,  N_RELN, 160, 160, 160, 0};
        sb.d[ns++] = SmallDesc{OUT_rel,  WO4,          entWOb + 4 * 160, arO,  N_RELN, 160, 160, 160, 0};
        sb.d[ns++] = SmallDesc{OUT_tim,  WI4 + 51200,  nullptr,          atI,  N_TIME,  80, 160, 160, 0};
        sb.d[ns++] = SmallDesc{OUT_tim,  WO4 + 51200,  nullptr,          atO,  N_TIME,  80, 160, 160, 0};
        sb.d[ns++] = SmallDesc{OUT_meta, rWI4,         relWIb + 4 * 160, bmI,  N_META, 160, 160, 160, 0};
        sb.d[ns++] = SmallDesc{OUT_meta, rWO4,         relWOb + 4 * 160, bmO,  N_META, 160, 160, 160, 0};
        sb.d[ns++] = SmallDesc{OUT_rel,  rWI4 + 25600, nullptr,          brI,  N_RELN, 160, 160, 160, 0};
        sb.d[ns++] = SmallDesc{OUT_rel,  rWO4 + 25600, nullptr,          brO,  N_RELN, 160, 160, 160, 0};
        sb.d[ns++] = SmallDesc{OUT_rel,  relWS + (size_t)4 * 25600, relWSb + 4 * 160,
                               hR4, N_RELN, 160, 160, 160, 0};
        sb.d[ns++] = SmallDesc{OUT_rel,  WI5,          entWIb + 5 * 160, ar5I, N_RELN, 160, 160, 160, 0};
        sb.d[ns++] = SmallDesc{OUT_rel,  WO5,          entWOb + 5 * 160, ar5O, N_RELN, 160, 160, 160, 0};
        sb.d[ns++] = SmallDesc{OUT_tim,  WI5 + 51200,  nullptr,          at5I, N_TIME,  80, 160, 160, 0};
        sb.d[ns++] = SmallDesc{OUT_tim,  WO5 + 51200,  nullptr,          at5O, N_TIME,  80, 160, 160, 0};
        sb.d[ns++] = SmallDesc{OUT_meta, rWI5,         relWIb + 5 * 160, bm5I, N_META, 160, 160, 160, 0};
        sb.d[ns++] = SmallDesc{OUT_meta, rWO5,         relWOb + 5 * 160, bm5O, N_META, 160, 160, 160, 0};
        sb.d[ns++] = SmallDesc{OUT_rel,  rWI5 + 25600, nullptr,          br5I, N_RELN, 160, 160, 160, 0};
        sb.d[ns++] = SmallDesc{OUT_rel,  rWO5 + 25600, nullptr,          br5O, N_RELN, 160, 160, 160, 0};
        sb.d[ns++] = SmallDesc{OUT_rel,  relWS + (size_t)5 * 25600, relWSb + 5 * 160,
                               hR5, N_RELN, 160, 160, 160, 0};
        gemm_small_batch<<<dim3(125, ns), 256, 0, stream>>>(sb);

        prepA(OUT_ent);
        big3(4, B5v);                                   // mean head GEMMs
        agg_ent_csr<<<(N_ENT * 40 + 255) / 256, 256, 0, stream>>>(
            rowptrE, packE, arI, arO, AI, AO, atI, atO, B5v, 0);   // mean_e
        big3(5, B1v);                                   // logstd head GEMMs
        agg_ent_sample<<<(N_ENT * 40 + 255) / 256, 256, 0, stream>>>(
            rowptrE, packE, ar5I, ar5O, AI, AO, at5I, at5O, B1v, B5v, noiseE, B5v); // z_e
        agg_rel_fused<<<N_RELN, 512, 0, stream>>>(
            rowptrR, packR, bmI, bmO, brI, brO, hR4, 0);           // mean_r
        agg_rel_sample<<<N_RELN, 512, 0, stream>>>(
            rowptrR, packR, bm5I, bm5O, br5I, br5O, hR5, hR4, noiseR, zR);          // z_r
    }

    // ---- decoder (layers 2,3) ----
    stage(2, B5v, zR, OUT_tim, OUT_meta, B1v, tim_o1, rel_o1, meta_o1, 1);
    stage(3, B1v, rel_o1, tim_o1, meta_o1, OUT_ento, OUT_timo, OUT_relo, OUT_metao, 0);
}

// Round 6
// 857.867 us; speedup vs baseline: 2.1154x; 1.2010x over previous
//
#include <hip/hip_runtime.h>
#include <math.h>

#define N_ENT     20000
#define N_RELN    400
#define N_TIME    366
#define N_META    800
#define NE        200000
#define NPE       80000
// dims: ENT=160, REL=160, TIME=80; DIN_E=400, DIN_R=320; NL=6

typedef __attribute__((ext_vector_type(8))) short short8;
typedef __attribute__((ext_vector_type(4))) float f32x4;

static __device__ __forceinline__ ushort f2bf(float x) {
    unsigned u = __float_as_uint(x);
    unsigned r = (u + 0x7FFF + ((u >> 16) & 1)) >> 16;   // RN-to-even
    return (ushort)r;
}
static __device__ __forceinline__ float bf2f(ushort b) {
    return __uint_as_float(((unsigned)b) << 16);
}

// ---------------------------------------------------------------------------
// Weight prep: 18 big 160x160 matrices -> transposed [col][k] bf16 hi/lo.
// ---------------------------------------------------------------------------
struct BPrep { const float* W[18]; };

__global__ __launch_bounds__(256) void bprep(BPrep bp, ushort* __restrict__ hi, ushort* __restrict__ lo)
{
    int idx = blockIdx.x * 256 + threadIdx.x;       // (s, n, kc): 18*160*20
    if (idx >= 18 * 160 * 20) return;
    int s = idx / 3200, rem = idx - s * 3200;
    int n = rem / 20, kc = rem - n * 20;
    const float* __restrict__ W = bp.W[s];
    ushort h[8], l[8];
#pragma unroll
    for (int j = 0; j < 8; ++j) {
        float x = W[(kc * 8 + j) * 160 + n];
        h[j] = f2bf(x);
        l[j] = f2bf(x - bf2f(h[j]));
    }
    size_t o = (size_t)s * 25600 + n * 160 + kc * 8;
    *(short8*)(hi + o) = *(short8*)h;
    *(short8*)(lo + o) = *(short8*)l;
}

// Activation split: f32 [M][160] -> bf16 hi/lo
__global__ __launch_bounds__(256) void aprep(const float* __restrict__ in,
                                             ushort* __restrict__ hi, ushort* __restrict__ lo, int n8)
{
    int i = blockIdx.x * 256 + threadIdx.x;
    if (i >= n8) return;
    const float* p = in + (size_t)i * 8;
    ushort h[8], l[8];
#pragma unroll
    for (int j = 0; j < 8; ++j) {
        float x = p[j];
        h[j] = f2bf(x);
        l[j] = f2bf(x - bf2f(h[j]));
    }
    *(short8*)(hi + (size_t)i * 8) = *(short8*)h;
    *(short8*)(lo + (size_t)i * 8) = *(short8*)l;
}

// ---------------------------------------------------------------------------
// Big GEMM v3 (MFMA split-bf16): C[M,160] = A[M,160]@B[160,160] (+bias).
// 256 thr = 4 waves; BM=64 (wave w -> rows w*16..+15); 10 col-tiles of 16;
// BK=32, 5 k-iters. 3 mfma (hh, lh, hl) per tile per iter.
// LDS rows padded to 40 ushorts (80B): 2-way bank max.
// k-map per lane: k = (lane>>4)*8 + j, applied identically to A and B
// (permutation-safe). C/D: col=lane&15, row=(lane>>4)*4+reg [m89].
// PROVEN in round 3 (passed, absmax 0.0078) — do not touch.
// ---------------------------------------------------------------------------
struct BigMF {
    const ushort* bh[3];
    const ushort* bl[3];
    const float*  bias[3];
    float*        C[3];
};

__global__ __launch_bounds__(256, 4) void gemm_big_mfma(
    const ushort* __restrict__ Ah, const ushort* __restrict__ Al, int M, BigMF bb)
{
    __shared__ ushort Ahi[64][40], Alo[64][40];
    __shared__ ushort Bhi[160][40], Blo[160][40];
    const int z = blockIdx.z;
    const ushort* __restrict__ Bh = bb.bh[z];
    const ushort* __restrict__ Bl = bb.bl[z];
    const float*  __restrict__ bias = bb.bias[z];
    float* __restrict__ C = bb.C[z];
    const int m0 = blockIdx.x * 64;
    const int t  = threadIdx.x;
    const int lane = t & 63, w = t >> 6;
    const int fr = lane & 15, fq = lane >> 4;

    f32x4 acc[10];
#pragma unroll
    for (int i = 0; i < 10; ++i) acc[i] = (f32x4){0.f, 0.f, 0.f, 0.f};

    for (int k0 = 0; k0 < 160; k0 += 32) {
        // stage A: 64 rows x 4 kchunks(8) -> 256 chunks, 1/thread
        {
            int r = t >> 2, kc = t & 3;
            int row = m0 + r;
            short8 vh = {0,0,0,0,0,0,0,0}, vl = {0,0,0,0,0,0,0,0};
            if (row < M) {
                size_t o = (size_t)row * 160 + k0 + kc * 8;
                vh = *(const short8*)(Ah + o);
                vl = *(const short8*)(Al + o);
            }
            *(short8*)&Ahi[r][kc * 8] = vh;
            *(short8*)&Alo[r][kc * 8] = vl;
        }
        // stage B: 160 cols x 4 kchunks = 640 chunks
#pragma unroll
        for (int i = 0; i < 3; ++i) {
            int idx = t + i * 256;
            if (idx < 640) {
                int col = idx >> 2, kc = idx & 3;
                size_t o = (size_t)col * 160 + k0 + kc * 8;
                *(short8*)&Bhi[col][kc * 8] = *(const short8*)(Bh + o);
                *(short8*)&Blo[col][kc * 8] = *(const short8*)(Bl + o);
            }
        }
        __syncthreads();
        short8 ah = *(const short8*)&Ahi[w * 16 + fr][fq * 8];
        short8 al = *(const short8*)&Alo[w * 16 + fr][fq * 8];
#pragma unroll
        for (int tt = 0; tt < 10; ++tt) {
            short8 bh = *(const short8*)&Bhi[tt * 16 + fr][fq * 8];
            short8 bl = *(const short8*)&Blo[tt * 16 + fr][fq * 8];
            acc[tt] = __builtin_amdgcn_mfma_f32_16x16x32_bf16(ah, bh, acc[tt], 0, 0, 0);
            acc[tt] = __builtin_amdgcn_mfma_f32_16x16x32_bf16(al, bh, acc[tt], 0, 0, 0);
            acc[tt] = __builtin_amdgcn_mfma_f32_16x16x32_bf16(ah, bl, acc[tt], 0, 0, 0);
        }
        __syncthreads();
    }
    // epilogue: bias + store. row = m0 + w*16 + fq*4 + q, col = tt*16 + fr
#pragma unroll
    for (int tt = 0; tt < 10; ++tt) {
        int col = tt * 16 + fr;
        float bv = bias ? bias[col] : 0.f;
#pragma unroll
        for (int q = 0; q < 4; ++q) {
            int row = m0 + w * 16 + fq * 4 + q;
            if (row < M) C[(size_t)row * 160 + col] = acc[tt][q] + bv;
        }
    }
}

// ---------------------------------------------------------------------------
// Small GEMM batch v2: register-tiled 4 rows x 4 cols per thread, K unroll 4.
// 64 FMA per 8 float4 loads, 16 independent acc chains (was 1 load : 4 FMA,
// single chain -> VALUBusy 4.7%). Same SmallDesc/launch shape as round 3.
// ---------------------------------------------------------------------------
struct SmallDesc {
    const float* A;
    const float* B;
    const float* bias;
    float*       C;
    int M, K, N, ldb, relu;
};
struct SmallBatch { SmallDesc d[18]; };

#define FMA4(acc, a, b) { acc.x = fmaf(a, b.x, acc.x); acc.y = fmaf(a, b.y, acc.y); \
                          acc.z = fmaf(a, b.z, acc.z); acc.w = fmaf(a, b.w, acc.w); }

__global__ __launch_bounds__(256) void gemm_small_batch(SmallBatch sb)
{
    SmallDesc dd = sb.d[blockIdx.y];
    int tid = blockIdx.x * 256 + threadIdx.x;
    int ng = dd.N >> 2;
    int mb = tid / ng;
    int nmb = (dd.M + 3) >> 2;
    if (mb >= nmb) return;
    int g = tid - mb * ng;
    int r0 = mb * 4;
    int mlast = dd.M - 1;
    const float* A0 = dd.A + (size_t)min(r0 + 0, mlast) * dd.K;
    const float* A1 = dd.A + (size_t)min(r0 + 1, mlast) * dd.K;
    const float* A2 = dd.A + (size_t)min(r0 + 2, mlast) * dd.K;
    const float* A3 = dd.A + (size_t)min(r0 + 3, mlast) * dd.K;
    const float* Bp = dd.B + g * 4;
    float4 c0 = {0,0,0,0}, c1 = {0,0,0,0}, c2 = {0,0,0,0}, c3 = {0,0,0,0};
    for (int k = 0; k < dd.K; k += 4) {
        float4 b0 = *(const float4*)(Bp + (size_t)(k + 0) * dd.ldb);
        float4 b1 = *(const float4*)(Bp + (size_t)(k + 1) * dd.ldb);
        float4 b2 = *(const float4*)(Bp + (size_t)(k + 2) * dd.ldb);
        float4 b3 = *(const float4*)(Bp + (size_t)(k + 3) * dd.ldb);
        float4 a0 = *(const float4*)(A0 + k);
        float4 a1 = *(const float4*)(A1 + k);
        float4 a2 = *(const float4*)(A2 + k);
        float4 a3 = *(const float4*)(A3 + k);
        FMA4(c0, a0.x, b0) FMA4(c0, a0.y, b1) FMA4(c0, a0.z, b2) FMA4(c0, a0.w, b3)
        FMA4(c1, a1.x, b0) FMA4(c1, a1.y, b1) FMA4(c1, a1.z, b2) FMA4(c1, a1.w, b3)
        FMA4(c2, a2.x, b0) FMA4(c2, a2.y, b1) FMA4(c2, a2.z, b2) FMA4(c2, a2.w, b3)
        FMA4(c3, a3.x, b0) FMA4(c3, a3.y, b1) FMA4(c3, a3.z, b2) FMA4(c3, a3.w, b3)
    }
    float4 bv = {0,0,0,0};
    if (dd.bias) bv = *(const float4*)(dd.bias + g * 4);
    c0.x += bv.x; c0.y += bv.y; c0.z += bv.z; c0.w += bv.w;
    c1.x += bv.x; c1.y += bv.y; c1.z += bv.z; c1.w += bv.w;
    c2.x += bv.x; c2.y += bv.y; c2.z += bv.z; c2.w += bv.w;
    c3.x += bv.x; c3.y += bv.y; c3.z += bv.z; c3.w += bv.w;
    if (dd.relu) {
        c0.x = fmaxf(c0.x, 0.f); c0.y = fmaxf(c0.y, 0.f); c0.z = fmaxf(c0.z, 0.f); c0.w = fmaxf(c0.w, 0.f);
        c1.x = fmaxf(c1.x, 0.f); c1.y = fmaxf(c1.y, 0.f); c1.z = fmaxf(c1.z, 0.f); c1.w = fmaxf(c1.w, 0.f);
        c2.x = fmaxf(c2.x, 0.f); c2.y = fmaxf(c2.y, 0.f); c2.z = fmaxf(c2.z, 0.f); c2.w = fmaxf(c2.w, 0.f);
        c3.x = fmaxf(c3.x, 0.f); c3.y = fmaxf(c3.y, 0.f); c3.z = fmaxf(c3.z, 0.f); c3.w = fmaxf(c3.w, 0.f);
    }
    float* C = dd.C + (size_t)r0 * dd.N + g * 4;
    if (r0 + 0 < dd.M) *(float4*)(C + 0 * (size_t)dd.N) = c0;
    if (r0 + 1 < dd.M) *(float4*)(C + 1 * (size_t)dd.N) = c1;
    if (r0 + 2 < dd.M) *(float4*)(C + 2 * (size_t)dd.N) = c2;
    if (r0 + 3 < dd.M) *(float4*)(C + 3 * (size_t)dd.N) = c3;
}

// ---------------------------------------------------------------------------
// CSR build with packed edge payload {i0, i1, i2, inv}.
// ---------------------------------------------------------------------------
__global__ void count_deg(const int* __restrict__ d, int E, int* __restrict__ cnt)
{
    int e = blockIdx.x * 256 + threadIdx.x;
    if (e < E) atomicAdd(&cnt[d[e]], 1);
}

__global__ __launch_bounds__(256) void scan_excl(int* __restrict__ cnt, int* __restrict__ rowptr, int n)
{
    __shared__ int ssum[256];
    int t = threadIdx.x;
    int chunk = (n + 255) / 256;
    int s0 = t * chunk; if (s0 > n) s0 = n;
    int s1 = s0 + chunk; if (s1 > n) s1 = n;
    int local = 0;
    for (int i = s0; i < s1; ++i) local += cnt[i];
    ssum[t] = local;
    __syncthreads();
    if (t == 0) {
        int acc = 0;
        for (int i = 0; i < 256; ++i) { int v = ssum[i]; ssum[i] = acc; acc += v; }
        rowptr[n] = acc;
    }
    __syncthreads();
    int acc = ssum[t];
    for (int i = s0; i < s1; ++i) {
        int v = cnt[i];
        rowptr[i] = acc;
        cnt[i] = acc;       // cnt becomes scatter cursor
        acc += v;
    }
}

__global__ void scatter_pack(const int* __restrict__ d, const int* __restrict__ a0,
                             const int* __restrict__ a1, const int* __restrict__ a2,
                             const int* __restrict__ inv, int E,
                             int* __restrict__ cursor, int4* __restrict__ pack)
{
    int e = blockIdx.x * 256 + threadIdx.x;
    if (e < E) {
        int p = atomicAdd(&cursor[d[e]], 1);
        int4 v;
        v.x = a0[e]; v.y = a1[e]; v.z = a2 ? a2[e] : 0; v.w = inv[e];
        pack[p] = v;
    }
}

// ---------------------------------------------------------------------------
// Ent aggregation (CSR, no atomics) + mean + ReLU. 40 thr/node, int4 payload.
// ---------------------------------------------------------------------------
__global__ __launch_bounds__(256) void agg_ent_csr(
    const int* __restrict__ rowptr, const int4* __restrict__ pack,
    const float* __restrict__ arI, const float* __restrict__ arO,
    const float* __restrict__ aeI, const float* __restrict__ aeO,
    const float* __restrict__ atI, const float* __restrict__ atO,
    float* __restrict__ H, int relu)
{
    int tid = blockIdx.x * 256 + threadIdx.x;
    int n = tid / 40;
    if (n >= N_ENT) return;
    int g = tid - n * 40;
    int c = g * 4;
    int b = rowptr[n], e = rowptr[n + 1];
    float ax = 0.f, ay = 0.f, az = 0.f, aw = 0.f;
    for (int j = b; j < e; ++j) {
        int4 p = pack[j];
        const float* t1 = (p.w ? arO : arI) + (size_t)p.x * 160 + c;
        const float* t2 = (p.w ? aeO : aeI) + (size_t)p.y * 160 + c;
        const float* t3 = (p.w ? atO : atI) + (size_t)p.z * 160 + c;
        float4 v1 = *(const float4*)t1;
        float4 v2 = *(const float4*)t2;
        float4 v3 = *(const float4*)t3;
        ax += v1.x + v2.x + v3.x;
        ay += v1.y + v2.y + v3.y;
        az += v1.z + v2.z + v3.z;
        aw += v1.w + v2.w + v3.w;
    }
    size_t idx = (size_t)n * 160 + c;
    float4 h = *(const float4*)(H + idx);
    if (e > b) {
        float s = 1.0f / (float)(e - b);
        h.x = fmaf(ax, s, h.x); h.y = fmaf(ay, s, h.y);
        h.z = fmaf(az, s, h.z); h.w = fmaf(aw, s, h.w);
    }
    if (relu) {
        h.x = fmaxf(h.x, 0.f); h.y = fmaxf(h.y, 0.f);
        h.z = fmaxf(h.z, 0.f); h.w = fmaxf(h.w, 0.f);
    }
    *(float4*)(H + idx) = h;
}

// Head-5 variant: logstd = Hs + agg/deg; out = mean + noise*exp(logstd)
__global__ __launch_bounds__(256) void agg_ent_sample(
    const int* __restrict__ rowptr, const int4* __restrict__ pack,
    const float* __restrict__ arI, const float* __restrict__ arO,
    const float* __restrict__ aeI, const float* __restrict__ aeO,
    const float* __restrict__ atI, const float* __restrict__ atO,
    const float* __restrict__ Hs, const float* __restrict__ mean,
    const float* __restrict__ noise, float* __restrict__ out)
{
    int tid = blockIdx.x * 256 + threadIdx.x;
    int n = tid / 40;
    if (n >= N_ENT) return;
    int g = tid - n * 40;
    int c = g * 4;
    int b = rowptr[n], e = rowptr[n + 1];
    float ax = 0.f, ay = 0.f, az = 0.f, aw = 0.f;
    for (int j = b; j < e; ++j) {
        int4 p = pack[j];
        const float* t1 = (p.w ? arO : arI) + (size_t)p.x * 160 + c;
        const float* t2 = (p.w ? aeO : aeI) + (size_t)p.y * 160 + c;
        const float* t3 = (p.w ? atO : atI) + (size_t)p.z * 160 + c;
        float4 v1 = *(const float4*)t1;
        float4 v2 = *(const float4*)t2;
        float4 v3 = *(const float4*)t3;
        ax += v1.x + v2.x + v3.x;
        ay += v1.y + v2.y + v3.y;
        az += v1.z + v2.z + v3.z;
        aw += v1.w + v2.w + v3.w;
    }
    size_t idx = (size_t)n * 160 + c;
    float4 h = *(const float4*)(Hs + idx);
    if (e > b) {
        float s = 1.0f / (float)(e - b);
        h.x = fmaf(ax, s, h.x); h.y = fmaf(ay, s, h.y);
        h.z = fmaf(az, s, h.z); h.w = fmaf(aw, s, h.w);
    }
    float4 mn = *(const float4*)(mean + idx);
    float4 nz = *(const float4*)(noise + idx);
    float4 zv;
    zv.x = fmaf(nz.x, expf(h.x), mn.x);
    zv.y = fmaf(nz.y, expf(h.y), mn.y);
    zv.z = fmaf(nz.z, expf(h.z), mn.z);
    zv.w = fmaf(nz.w, expf(h.w), mn.w);
    *(float4*)(out + idx) = zv;
}

// ---------------------------------------------------------------------------
// Rel aggregation: block per node, 12 segments x 40 col-groups, LDS reduce.
// ---------------------------------------------------------------------------
__global__ __launch_bounds__(512) void agg_rel_fused(
    const int* __restrict__ rowptr, const int4* __restrict__ pack,
    const float* __restrict__ bmI, const float* __restrict__ bmO,
    const float* __restrict__ brI, const float* __restrict__ brO,
    float* __restrict__ H, int relu)
{
    __shared__ float part[12][40][4];
    int n = blockIdx.x;
    int t = threadIdx.x;
    int g = t % 40, s = t / 40;
    int b = rowptr[n], e = rowptr[n + 1];
    if (s < 12) {
        int c = g * 4;
        float ax = 0.f, ay = 0.f, az = 0.f, aw = 0.f;
        for (int j = b + s; j < e; j += 12) {
            int4 p = pack[j];
            const float* pm = (p.w ? bmO : bmI) + (size_t)p.x * 160 + c;
            const float* pr = (p.w ? brO : brI) + (size_t)p.y * 160 + c;
            float4 vm = *(const float4*)pm;
            float4 vr = *(const float4*)pr;
            ax += vm.x + vr.x; ay += vm.y + vr.y;
            az += vm.z + vr.z; aw += vm.w + vr.w;
        }
        part[s][g][0] = ax; part[s][g][1] = ay;
        part[s][g][2] = az; part[s][g][3] = aw;
    }
    __syncthreads();
    if (t < 160) {
        int gg = t >> 2, q = t & 3;
        float acc = 0.f;
#pragma unroll
        for (int s2 = 0; s2 < 12; ++s2) acc += part[s2][gg][q];
        size_t idx = (size_t)n * 160 + t;
        float h = H[idx];
        int d = e - b;
        if (d > 0) h = fmaf(acc, 1.0f / (float)d, h);
        if (relu) h = fmaxf(h, 0.f);
        H[idx] = h;
    }
}

__global__ __launch_bounds__(512) void agg_rel_sample(
    const int* __restrict__ rowptr, const int4* __restrict__ pack,
    const float* __restrict__ bmI, const float* __restrict__ bmO,
    const float* __restrict__ brI, const float* __restrict__ brO,
    const float* __restrict__ Hs, const float* __restrict__ mean,
    const float* __restrict__ noise, float* __restrict__ out)
{
    __shared__ float part[12][40][4];
    int n = blockIdx.x;
    int t = threadIdx.x;
    int g = t % 40, s = t / 40;
    int b = rowptr[n], e = rowptr[n + 1];
    if (s < 12) {
        int c = g * 4;
        float ax = 0.f, ay = 0.f, az = 0.f, aw = 0.f;
        for (int j = b + s; j < e; j += 12) {
            int4 p = pack[j];
            const float* pm = (p.w ? bmO : bmI) + (size_t)p.x * 160 + c;
            const float* pr = (p.w ? brO : brI) + (size_t)p.y * 160 + c;
            float4 vm = *(const float4*)pm;
            float4 vr = *(const float4*)pr;
            ax += vm.x + vr.x; ay += vm.y + vr.y;
            az += vm.z + vr.z; aw += vm.w + vr.w;
        }
        part[s][g][0] = ax; part[s][g][1] = ay;
        part[s][g][2] = az; part[s][g][3] = aw;
    }
    __syncthreads();
    if (t < 160) {
        int gg = t >> 2, q = t & 3;
        float acc = 0.f;
#pragma unroll
        for (int s2 = 0; s2 < 12; ++s2) acc += part[s2][gg][q];
        size_t idx = (size_t)n * 160 + t;
        float h = Hs[idx];
        int d = e - b;
        if (d > 0) h = fmaf(acc, 1.0f / (float)d, h);
        out[idx] = fmaf(noise[idx], expf(h), mean[idx]);
    }
}

// ---------------------------------------------------------------------------
extern "C" void kernel_launch(void* const* d_in, const int* in_sizes, int n_in,
                              void* d_out, int out_size, void* d_ws, size_t ws_size,
                              hipStream_t stream)
{
    const float* ent0   = (const float*)d_in[0];
    const float* rel0   = (const float*)d_in[1];
    const float* tim0   = (const float*)d_in[2];
    const float* meta0  = (const float*)d_in[3];
    const float* noiseE = (const float*)d_in[4];
    const float* noiseR = (const float*)d_in[5];
    const float* entWI  = (const float*)d_in[6];
    const float* entWIb = (const float*)d_in[7];
    const float* entWO  = (const float*)d_in[8];
    const float* entWOb = (const float*)d_in[9];
    const float* entWS  = (const float*)d_in[10];
    const float* entWSb = (const float*)d_in[11];
    const float* entWT  = (const float*)d_in[12];
    const float* entWTb = (const float*)d_in[13];
    const float* relWI  = (const float*)d_in[14];
    const float* relWIb = (const float*)d_in[15];
    const float* relWO  = (const float*)d_in[16];
    const float* relWOb = (const float*)d_in[17];
    const float* relWS  = (const float*)d_in[18];
    const float* relWSb = (const float*)d_in[19];
    const float* relWM  = (const float*)d_in[20];
    const float* relWMb = (const float*)d_in[21];
    const int* src    = (const int*)d_in[22];
    const int* dst    = (const int*)d_in[23];
    const int* e_rel  = (const int*)d_in[24];
    const int* e_time = (const int*)d_in[25];
    const int* e_inv  = (const int*)d_in[26];
    const int* p_src  = (const int*)d_in[27];
    const int* p_dst  = (const int*)d_in[28];
    const int* p_rel  = (const int*)d_in[29];
    const int* p_inv  = (const int*)d_in[30];

    float* out = (float*)d_out;
    float* OUT_ent   = out + 0;
    float* OUT_ento  = out + 3200000;
    float* OUT_rel   = out + 6400000;
    float* OUT_relo  = out + 6464000;
    float* OUT_tim   = out + 6528000;
    float* OUT_timo  = out + 6557280;
    float* OUT_meta  = out + 6586560;
    float* OUT_metao = out + 6714560;

    // ---- workspace carve-out (~76 MB) ----
    char* wsp = (char*)d_ws;
    size_t off = 0;
    auto allocF = [&](size_t n) -> float* {
        float* p = (float*)(wsp + off);
        off += ((n * sizeof(float) + 255) & ~(size_t)255);
        return p;
    };
    auto allocU = [&](size_t n) -> ushort* {
        ushort* p = (ushort*)(wsp + off);
        off += ((n * sizeof(ushort) + 255) & ~(size_t)255);
        return p;
    };
    auto allocI = [&](size_t n) -> int* {
        int* p = (int*)(wsp + off);
        off += ((n * sizeof(int) + 255) & ~(size_t)255);
        return p;
    };
    float* AI      = allocF(3200000);
    float* AO      = allocF(3200000);
    float* B1v     = allocF(3200000);   // ent1 / Hs(logstd_e) / ent_o1
    float* B5v     = allocF(3200000);   // mean_e / z_e
    float* tim1    = allocF(29280);
    float* tim_o1  = allocF(29280);
    float* rel1    = allocF(64000);
    float* rel_o1  = allocF(64000);
    float* meta1   = allocF(128000);
    float* meta_o1 = allocF(128000);
    float* arI  = allocF(64000);
    float* arO  = allocF(64000);
    float* atI  = allocF(58560);
    float* atO  = allocF(58560);
    float* bmI  = allocF(128000);
    float* bmO  = allocF(128000);
    float* brI  = allocF(64000);
    float* brO  = allocF(64000);
    float* ar5I = allocF(64000);
    float* ar5O = allocF(64000);
    float* at5I = allocF(58560);
    float* at5O = allocF(58560);
    float* bm5I = allocF(128000);
    float* bm5O = allocF(128000);
    float* br5I = allocF(64000);
    float* br5O = allocF(64000);
    float* hR4  = allocF(64000);        // mean_r
    float* hR5  = allocF(64000);        // Hs for rel logstd
    float* zR   = allocF(64000);
    ushort* Ahg = allocU(3200000);      // activation hi
    ushort* Alg = allocU(3200000);      // activation lo
    ushort* Bhg = allocU(18 * 25600);   // weight hi (transposed)
    ushort* Blg = allocU(18 * 25600);
    int*  cntE    = allocI(N_ENT);
    int*  rowptrE = allocI(N_ENT + 1);
    int4* packE   = (int4*)allocI(NE * 4);
    int*  cntR    = allocI(N_RELN);
    int*  rowptrR = allocI(N_RELN + 1);
    int4* packR   = (int4*)allocI(NPE * 4);
    if (ws_size < off) return;  // loud failure (output stays poisoned)

    // ---- CSR build + packed payloads ----
    hipMemsetAsync(cntE, 0, N_ENT * sizeof(int), stream);
    hipMemsetAsync(cntR, 0, N_RELN * sizeof(int), stream);
    count_deg<<<(NE + 255) / 256, 256, 0, stream>>>(dst, NE, cntE);
    count_deg<<<(NPE + 255) / 256, 256, 0, stream>>>(p_dst, NPE, cntR);
    scan_excl<<<1, 256, 0, stream>>>(cntE, rowptrE, N_ENT);
    scan_excl<<<1, 256, 0, stream>>>(cntR, rowptrR, N_RELN);
    scatter_pack<<<(NE + 255) / 256, 256, 0, stream>>>(dst, e_rel, src, e_time, e_inv, NE, cntE, packE);
    scatter_pack<<<(NPE + 255) / 256, 256, 0, stream>>>(p_dst, p_rel, p_src, nullptr, p_inv, NPE, cntR, packR);

    // ---- weight prep: slots li*3 + {0:WIent, 1:WOent, 2:WS} ----
    BPrep bp;
    for (int li = 0; li < 6; ++li) {
        bp.W[li * 3 + 0] = entWI + (size_t)li * 64000 + 25600;
        bp.W[li * 3 + 1] = entWO + (size_t)li * 64000 + 25600;
        bp.W[li * 3 + 2] = entWS + (size_t)li * 25600;
    }
    bprep<<<(18 * 160 * 20 + 255) / 256, 256, 0, stream>>>(bp, Bhg, Blg);

    auto big3 = [&](int li, float* entOut) {
        BigMF bb;
        for (int j = 0; j < 3; ++j) {
            bb.bh[j] = Bhg + (size_t)(li * 3 + j) * 25600;
            bb.bl[j] = Blg + (size_t)(li * 3 + j) * 25600;
        }
        bb.bias[0] = nullptr; bb.bias[1] = nullptr; bb.bias[2] = entWSb + li * 160;
        bb.C[0] = AI; bb.C[1] = AO; bb.C[2] = entOut;
        gemm_big_mfma<<<dim3(313, 1, 3), 256, 0, stream>>>(Ahg, Alg, N_ENT, bb);
    };
    auto prepA = [&](const float* entIn) {
        aprep<<<(400000 + 255) / 256, 256, 0, stream>>>(entIn, Ahg, Alg, 400000);
    };

    // ---- normal stage (li in {0,1,2,3}) ----
    auto stage = [&](int li, const float* entIn, const float* relIn, const float* timIn,
                     const float* metaIn, float* entOut, float* timOut,
                     float* relOut, float* metaOut, int act) {
        const float* WI  = entWI + (size_t)li * 64000;
        const float* WO  = entWO + (size_t)li * 64000;
        const float* rWI = relWI + (size_t)li * 51200;
        const float* rWO = relWO + (size_t)li * 51200;

        SmallBatch sb{};
        int ns = 0;
        sb.d[ns++] = SmallDesc{relIn,  WI,          entWIb + li * 160, arI,    N_RELN, 160, 160, 160, 0};
        sb.d[ns++] = SmallDesc{relIn,  WO,          entWOb + li * 160, arO,    N_RELN, 160, 160, 160, 0};
        sb.d[ns++] = SmallDesc{timIn,  WI + 51200,  nullptr,           atI,    N_TIME,  80, 160, 160, 0};
        sb.d[ns++] = SmallDesc{timIn,  WO + 51200,  nullptr,           atO,    N_TIME,  80, 160, 160, 0};
        if (timOut)
            sb.d[ns++] = SmallDesc{timIn, entWT + (size_t)li * 6400, entWTb + li * 80,
                                   timOut, N_TIME, 80, 80, 80, act};
        sb.d[ns++] = SmallDesc{metaIn, rWI,         relWIb + li * 160, bmI,    N_META, 160, 160, 160, 0};
        sb.d[ns++] = SmallDesc{metaIn, rWO,         relWOb + li * 160, bmO,    N_META, 160, 160, 160, 0};
        sb.d[ns++] = SmallDesc{relIn,  rWI + 25600, nullptr,           brI,    N_RELN, 160, 160, 160, 0};
        sb.d[ns++] = SmallDesc{relIn,  rWO + 25600, nullptr,           brO,    N_RELN, 160, 160, 160, 0};
        sb.d[ns++] = SmallDesc{relIn,  relWS + (size_t)li * 25600, relWSb + li * 160,
                               relOut, N_RELN, 160, 160, 160, 0};
        if (metaOut)
            sb.d[ns++] = SmallDesc{metaIn, relWM + (size_t)li * 25600, relWMb + li * 160,
                                   metaOut, N_META, 160, 160, 160, act};
        gemm_small_batch<<<dim3(32, ns), 256, 0, stream>>>(sb);

        prepA(entIn);
        big3(li, entOut);
        agg_ent_csr<<<(N_ENT * 40 + 255) / 256, 256, 0, stream>>>(
            rowptrE, packE, arI, arO, AI, AO, atI, atO, entOut, act);
        agg_rel_fused<<<N_RELN, 512, 0, stream>>>(
            rowptrR, packR, bmI, bmO, brI, brO, relOut, act);
    };

    // ---- encoder ----
    stage(0, ent0, rel0, tim0, meta0, B1v, tim1, rel1, meta1, 1);
    stage(1, B1v, rel1, tim1, meta1, OUT_ent, OUT_tim, OUT_rel, OUT_meta, 0);

    // ---- variational heads (li=4 mean, li=5 log_std), fused sampling ----
    {
        const float* WI4  = entWI + (size_t)4 * 64000;
        const float* WO4  = entWO + (size_t)4 * 64000;
        const float* WI5  = entWI + (size_t)5 * 64000;
        const float* WO5  = entWO + (size_t)5 * 64000;
        const float* rWI4 = relWI + (size_t)4 * 51200;
        const float* rWO4 = relWO + (size_t)4 * 51200;
        const float* rWI5 = relWI + (size_t)5 * 51200;
        const float* rWO5 = relWO + (size_t)5 * 51200;

        SmallBatch sb{};
        int ns = 0;
        sb.d[ns++] = SmallDesc{OUT_rel,  WI4,          entWIb + 4 * 160, arI,  N_RELN, 160, 160, 160, 0};
        sb.d[ns++] = SmallDesc{OUT_rel,  WO4,          entWOb + 4 * 160, arO,  N_RELN, 160, 160, 160, 0};
        sb.d[ns++] = SmallDesc{OUT_tim,  WI4 + 51200,  nullptr,          atI,  N_TIME,  80, 160, 160, 0};
        sb.d[ns++] = SmallDesc{OUT_tim,  WO4 + 51200,  nullptr,          atO,  N_TIME,  80, 160, 160, 0};
        sb.d[ns++] = SmallDesc{OUT_meta, rWI4,         relWIb + 4 * 160, bmI,  N_META, 160, 160, 160, 0};
        sb.d[ns++] = SmallDesc{OUT_meta, rWO4,         relWOb + 4 * 160, bmO,  N_META, 160, 160, 160, 0};
        sb.d[ns++] = SmallDesc{OUT_rel,  rWI4 + 25600, nullptr,          brI,  N_RELN, 160, 160, 160, 0};
        sb.d[ns++] = SmallDesc{OUT_rel,  rWO4 + 25600, nullptr,          brO,  N_RELN, 160, 160, 160, 0};
        sb.d[ns++] = SmallDesc{OUT_rel,  relWS + (size_t)4 * 25600, relWSb + 4 * 160,
                               hR4, N_RELN, 160, 160, 160, 0};
        sb.d[ns++] = SmallDesc{OUT_rel,  WI5,          entWIb + 5 * 160, ar5I, N_RELN, 160, 160, 160, 0};
        sb.d[ns++] = SmallDesc{OUT_rel,  WO5,          entWOb + 5 * 160, ar5O, N_RELN, 160, 160, 160, 0};
        sb.d[ns++] = SmallDesc{OUT_tim,  WI5 + 51200,  nullptr,          at5I, N_TIME,  80, 160, 160, 0};
        sb.d[ns++] = SmallDesc{OUT_tim,  WO5 + 51200,  nullptr,          at5O, N_TIME,  80, 160, 160, 0};
        sb.d[ns++] = SmallDesc{OUT_meta, rWI5,         relWIb + 5 * 160, bm5I, N_META, 160, 160, 160, 0};
        sb.d[ns++] = SmallDesc{OUT_meta, rWO5,         relWOb + 5 * 160, bm5O, N_META, 160, 160, 160, 0};
        sb.d[ns++] = SmallDesc{OUT_rel,  rWI5 + 25600, nullptr,          br5I, N_RELN, 160, 160, 160, 0};
        sb.d[ns++] = SmallDesc{OUT_rel,  rWO5 + 25600, nullptr,          br5O, N_RELN, 160, 160, 160, 0};
        sb.d[ns++] = SmallDesc{OUT_rel,  relWS + (size_t)5 * 25600, relWSb + 5 * 160,
                               hR5, N_RELN, 160, 160, 160, 0};
        gemm_small_batch<<<dim3(32, ns), 256, 0, stream>>>(sb);

        prepA(OUT_ent);
        big3(4, B5v);                                   // mean head GEMMs
        agg_ent_csr<<<(N_ENT * 40 + 255) / 256, 256, 0, stream>>>(
            rowptrE, packE, arI, arO, AI, AO, atI, atO, B5v, 0);   // mean_e
        big3(5, B1v);                                   // logstd head GEMMs
        agg_ent_sample<<<(N_ENT * 40 + 255) / 256, 256, 0, stream>>>(
            rowptrE, packE, ar5I, ar5O, AI, AO, at5I, at5O, B1v, B5v, noiseE, B5v); // z_e
        agg_rel_fused<<<N_RELN, 512, 0, stream>>>(
            rowptrR, packR, bmI, bmO, brI, brO, hR4, 0);           // mean_r
        agg_rel_sample<<<N_RELN, 512, 0, stream>>>(
            rowptrR, packR, bm5I, bm5O, br5I, br5O, hR5, hR4, noiseR, zR);          // z_r
    }

    // ---- decoder (layers 2,3) ----
    stage(2, B5v, zR, OUT_tim, OUT_meta, B1v, tim_o1, rel_o1, meta_o1, 1);
    stage(3, B1v, rel_o1, tim_o1, meta_o1, OUT_ento, OUT_timo, OUT_relo, OUT_metao, 0);
}